// Round 15
// baseline (9453.847 us; speedup 1.0000x reference)
//
#include <hip/hip_runtime.h>
#include <hip/hip_bf16.h>

#define B_   256
#define T_   64
#define OBS_ 1024
#define ACT_ 6
#define STO_ 32
#define HID_ 1024

using bf16 = __bf16;
typedef __attribute__((ext_vector_type(8))) __bf16 bf16x8;
typedef __attribute__((ext_vector_type(4))) float f32x4;

__device__ __forceinline__ f32x4 MF(bf16x8 a, bf16x8 b, f32x4 c) {
  return __builtin_amdgcn_mfma_f32_16x16x32_bf16(a, b, c, 0, 0, 0);
}

// ---------------- prologue: weights + obs -> bf16 ----------------
struct CvtArgs {
  const float *in_w2, *gru_wih, *gru_whh, *pr_w1, *pr_w2, *po_w1, *po_w2;
  const float *pr_mw, *pr_sw, *po_mw, *po_sw, *obs;
  bf16 *w_in2b, *w_wihb, *w_whhb, *w_pr1b, *w_pr2b, *w_po1hb, *w_po1ob, *w_po2b, *w_headb, *obsb;
};

__global__ void k_cvtall(CvtArgs a) {
  const int row = blockIdx.x;            // 28800 rows
  const float* src; bf16* dst;
  if      (row < 1024)  { src = a.in_w2   + (size_t)row * 1024;               dst = a.w_in2b  + (size_t)row * 1024; }
  else if (row < 4096)  { int r = row - 1024;  src = a.gru_wih + (size_t)r * 1024;        dst = a.w_wihb  + (size_t)r * 1024; }
  else if (row < 7168)  { int r = row - 4096;  src = a.gru_whh + (size_t)r * 1024;        dst = a.w_whhb  + (size_t)r * 1024; }
  else if (row < 8192)  { int r = row - 7168;  src = a.pr_w1   + (size_t)r * 1024;        dst = a.w_pr1b  + (size_t)r * 1024; }
  else if (row < 9216)  { int r = row - 8192;  src = a.pr_w2   + (size_t)r * 1024;        dst = a.w_pr2b  + (size_t)r * 1024; }
  else if (row < 10240) { int r = row - 9216;  src = a.po_w1   + (size_t)r * 2048;        dst = a.w_po1hb + (size_t)r * 1024; }
  else if (row < 11264) { int r = row - 10240; src = a.po_w1   + (size_t)r * 2048 + 1024; dst = a.w_po1ob + (size_t)r * 1024; }
  else if (row < 12288) { int r = row - 11264; src = a.po_w2   + (size_t)r * 1024;        dst = a.w_po2b  + (size_t)r * 1024; }
  else if (row < 12416) {
    int r = row - 12288;
    const float* hs[4] = { a.pr_mw, a.pr_sw, a.po_mw, a.po_sw };
    src = hs[r >> 5] + (size_t)(r & 31) * 1024;
    dst = a.w_headb + (size_t)r * 1024;
  }
  else { int r = row - 12416; src = a.obs + (size_t)r * 1024; dst = a.obsb + (size_t)r * 1024; }
  const int c = threadIdx.x * 4;
  float4 f = *(const float4*)(src + c);
  dst[c] = (bf16)f.x; dst[c + 1] = (bf16)f.y; dst[c + 2] = (bf16)f.z; dst[c + 3] = (bf16)f.w;
}

__global__ void k_init(const float* __restrict__ in_b1, bf16* __restrict__ x1b,
                       bf16* __restrict__ hbA, bf16* __restrict__ hbB,
                       float* __restrict__ hfA, float* __restrict__ hfB) {
  const int i = blockIdx.x * 256 + threadIdx.x;      // < 262144
  x1b[i] = (bf16)fmaxf(in_b1[i & 1023], 0.f);        // z0=0, a0=0
  hbA[i] = (bf16)0.f; hbB[i] = (bf16)0.f;
  hfA[i] = 0.f; hfB[i] = 0.f;
}

// ---------------- GB2 split-K dual-GEMM tile body (R12-verified) ----------------
struct GB2 {
  const bf16 *A1, *A2, *W1, *W2;
  const float* bias;
  bf16* out;
  int lda1, lda2, K1, kseg;
};

__device__ __forceinline__ void gb2_run(const GB2& g, int tile, float* sh) {
  const int tid = threadIdx.x, lane = tid & 63, kw = tid >> 6;
  const int l15 = lane & 15, kg = lane >> 4, kq = kg * 8, rq = kg * 4;
  const int m0 = (tile & 15) * 16, n0 = (tile >> 4) * 64;
  const int kb = kw * g.kseg;

  const bf16* __restrict__ ap;
  const bf16* __restrict__ wp;
  if (kb < g.K1) {
    ap = g.A1 + (size_t)(m0 + l15) * g.lda1 + kb + kq;
    wp = g.W1 + (size_t)(n0 + l15) * 1024 + kb + kq;
  } else {
    ap = g.A2 + (size_t)(m0 + l15) * g.lda2 + (kb - g.K1) + kq;
    wp = g.W2 + (size_t)(n0 + l15) * 1024 + (kb - g.K1) + kq;
  }
  f32x4 c0{0.f,0.f,0.f,0.f}, c1 = c0, c2 = c0, c3 = c0;
  #pragma unroll 8
  for (int k = 0; k < g.kseg; k += 32) {
    bf16x8 af = *(const bf16x8*)(ap + k);
    c0 = MF(af, *(const bf16x8*)(wp + k            ), c0);
    c1 = MF(af, *(const bf16x8*)(wp + 16 * 1024 + k), c1);
    c2 = MF(af, *(const bf16x8*)(wp + 32 * 1024 + k), c2);
    c3 = MF(af, *(const bf16x8*)(wp + 48 * 1024 + k), c3);
  }
  f32x4 cc[4] = {c0, c1, c2, c3};
  if (kw) {
    float* s = sh + (kw - 1) * 1056;
    #pragma unroll
    for (int t2 = 0; t2 < 4; ++t2)
      #pragma unroll
      for (int r = 0; r < 4; ++r)
        s[(rq + r) * 66 + t2 * 16 + l15] = cc[t2][r];
  }
  __syncthreads();
  if (kw == 0) {
    #pragma unroll
    for (int t2 = 0; t2 < 4; ++t2) {
      const int n = n0 + t2 * 16 + l15;
      const float bv = g.bias[n];
      #pragma unroll
      for (int r = 0; r < 4; ++r) {
        float v = cc[t2][r] + bv;
        #pragma unroll
        for (int s = 0; s < 3; ++s)
          v += sh[s * 1056 + (rq + r) * 66 + t2 * 16 + l15];
        g.out[(size_t)(m0 + rq + r) * 1024 + n] = (bf16)fmaxf(v, 0.f);
      }
    }
  }
}

__global__ __launch_bounds__(256, 4) void k_l1(GB2 g0, GB2 g1, int s1) {
  __shared__ float sh[3 * 1056];
  if ((int)blockIdx.x < s1) gb2_run(g0, blockIdx.x, sh);
  else                      gb2_run(g1, blockIdx.x - s1, sh);
}

// ---------------- heads_p block body (4 waves, 256 thr) ----------------
__device__ __forceinline__ void heads_p_run(
    int g2, int tlab, const bf16* __restrict__ p2b, const bf16* __restrict__ whead,
    const float* __restrict__ pr_mb, const float* __restrict__ pr_sb,
    float* __restrict__ pm, float* __restrict__ ps, float* shp) {
  const int tid = threadIdx.x, lane = tid & 63, wv = tid >> 6;
  const int l15 = lane & 15, kg = lane >> 4, kq = kg * 8;
  const int m0 = g2 * 16;
  {
    f32x4 c{0.f, 0.f, 0.f, 0.f};
    const bf16* __restrict__ ap = p2b + (size_t)(m0 + l15) * 1024 + kq;
    const bf16* __restrict__ wp = whead + (size_t)(wv * 16 + l15) * 1024 + kq;   // rows 0..63 = pr_m, pr_s
    #pragma unroll 4
    for (int k = 0; k < 1024; k += 32) {
      bf16x8 af = *(const bf16x8*)(ap + k);
      c = MF(af, *(const bf16x8*)(wp + k), c);
    }
    #pragma unroll
    for (int r = 0; r < 4; ++r)
      shp[(kg * 4 + r) * 64 + wv * 16 + l15] = c[r];
  }
  __syncthreads();
  #pragma unroll
  for (int rep = 0; rep < 4; ++rep) {
    const int idx = rep * 256 + tid;    // 16 x 64
    const int r = idx >> 6, c = idx & 63;
    const float v = shp[r * 64 + c];
    const size_t ob = ((size_t)(m0 + r) * T_ + tlab) * STO_ + (c & 31);
    if (c < 32) pm[ob] = v + pr_mb[c];
    else        ps[ob] = __expf(fminf(fmaxf(v + pr_sb[c - 32], -5.f), 2.f));
  }
}

// ---------------- L2: q1 || pr1 || heads_p(t-1)  (528 blocks x 256 thr) ----------------
__global__ __launch_bounds__(256, 4) void k_l2(
    GB2 g0, GB2 g1,
    const bf16* __restrict__ p2b, const bf16* __restrict__ whead,
    const float* __restrict__ pr_mb, const float* __restrict__ pr_sb,
    float* __restrict__ pm, float* __restrict__ ps, int t) {
  __shared__ float sh[3 * 1056];
  const int bid = blockIdx.x;
  if (bid < 256)      gb2_run(g0, bid, sh);
  else if (bid < 512) gb2_run(g1, bid - 256, sh);
  else if (t > 0)     heads_p_run(bid - 512, t - 1, p2b, whead, pr_mb, pr_sb, pm, ps, sh);
}

// ---------------- epilogue heads_p for t = T-1 ----------------
__global__ __launch_bounds__(256, 4) void k_hp(
    const bf16* __restrict__ p2b, const bf16* __restrict__ whead,
    const float* __restrict__ pr_mb, const float* __restrict__ pr_sb,
    float* __restrict__ pm, float* __restrict__ ps) {
  __shared__ float sh[1024];
  heads_p_run(blockIdx.x, T_ - 1, p2b, whead, pr_mb, pr_sb, pm, ps, sh);
}

// ---------------- gh + gi + GRU gates fused (R12-verified) ----------------
__global__ __launch_bounds__(512, 2) void k_gru(
    const bf16* __restrict__ hbPrev, const float* __restrict__ hfPrev,
    bf16* __restrict__ hbCur, float* __restrict__ hfCur,
    const bf16* __restrict__ x2b, const bf16* __restrict__ wih,
    const bf16* __restrict__ whh, const float* __restrict__ bih,
    const float* __restrict__ bhh, float* __restrict__ feat, int t) {
  __shared__ float sh[4 * 1088];
  const int mt = blockIdx.x & 3, cs = blockIdx.x >> 2;
  const int tid = threadIdx.x, lane = tid & 63, wv = tid >> 6;
  const int msub = wv & 3, kw = wv >> 2;
  const int l15 = lane & 15, kg = lane >> 4, kq = kg * 8, rq = kg * 4;
  const int mrow = mt * 64 + msub * 16;
  const int c0 = cs * 16;
  const int kb = kw * 512;
  const size_t GOFF = (size_t)1024 * 1024;

  f32x4 ghR{0.f,0.f,0.f,0.f}, ghZ = ghR, ghN = ghR, giR = ghR, giZ = ghR, giN = ghR;
  {
    const bf16* __restrict__ ap = hbPrev + (size_t)(mrow + l15) * 1024 + kb + kq;
    const bf16* __restrict__ wr = whh + (size_t)(c0 + l15) * 1024 + kb + kq;
    #pragma unroll 4
    for (int k = 0; k < 512; k += 32) {
      bf16x8 af = *(const bf16x8*)(ap + k);
      ghR = MF(af, *(const bf16x8*)(wr + k           ), ghR);
      ghZ = MF(af, *(const bf16x8*)(wr + GOFF + k    ), ghZ);
      ghN = MF(af, *(const bf16x8*)(wr + 2 * GOFF + k), ghN);
    }
  }
  {
    const bf16* __restrict__ ap = x2b + (size_t)(mrow + l15) * 1024 + kb + kq;
    const bf16* __restrict__ wr = wih + (size_t)(c0 + l15) * 1024 + kb + kq;
    #pragma unroll 4
    for (int k = 0; k < 512; k += 32) {
      bf16x8 af = *(const bf16x8*)(ap + k);
      giR = MF(af, *(const bf16x8*)(wr + k           ), giR);
      giZ = MF(af, *(const bf16x8*)(wr + GOFF + k    ), giZ);
      giN = MF(af, *(const bf16x8*)(wr + 2 * GOFF + k), giN);
    }
  }
  f32x4 sR = ghR + giR, sZ = ghZ + giZ;
  if (kw) {
    float* s = sh + msub * 1088;
    #pragma unroll
    for (int r = 0; r < 4; ++r) {
      s[      (rq + r) * 17 + l15] = sR[r];
      s[272 + (rq + r) * 17 + l15] = sZ[r];
      s[544 + (rq + r) * 17 + l15] = giN[r];
      s[816 + (rq + r) * 17 + l15] = ghN[r];
    }
  }
  __syncthreads();
  if (kw == 0) {
    const int c = c0 + l15;
    const float bir = bih[c], biz = bih[1024 + c], bin_ = bih[2048 + c];
    const float bhr = bhh[c], bhz = bhh[1024 + c], bhn = bhh[2048 + c];
    const float* s = sh + msub * 1088;
    #pragma unroll
    for (int r = 0; r < 4; ++r) {
      const float vr  = sR[r]  + s[      (rq + r) * 17 + l15];
      const float vz  = sZ[r]  + s[272 + (rq + r) * 17 + l15];
      const float vin = giN[r] + s[544 + (rq + r) * 17 + l15];
      const float vhn = ghN[r] + s[816 + (rq + r) * 17 + l15];
      const int row = mrow + rq + r;
      float rr = vr + bir + bhr;
      float zz = vz + biz + bhz;
      rr = 1.f / (1.f + __expf(-rr));
      zz = 1.f / (1.f + __expf(-zz));
      const float nn = tanhf(vin + bin_ + rr * (vhn + bhn));
      const float h2 = (1.f - zz) * nn + zz * hfPrev[(size_t)row * 1024 + c];
      hbCur[(size_t)row * 1024 + c] = (bf16)h2;
      hfCur[(size_t)row * 1024 + c] = h2;
      feat[((size_t)row * T_ + t) * 1056 + c] = h2;
    }
  }
}

// ---------------- fin4: [q2-in-LDS + heads_q + z + x1 + x2] || pr2 ----------------
// bid<128: fin role, g = bid>>3 (16 rows), nt = bid&7 (128 x2-cols).
// bid>=128: pr2 tile, idx=bid-128: mt=idx&15, nc=idx>>4 (256 cols), 16 waves x 1 frag.
__global__ __launch_bounds__(1024, 1) void k_fin4(
    const bf16* __restrict__ q1b, const bf16* __restrict__ p1b,
    const bf16* __restrict__ w_po2, const float* __restrict__ b_po2,
    const bf16* __restrict__ w_pr2, const float* __restrict__ b_pr2,
    bf16* __restrict__ p2b,
    const bf16* __restrict__ whead, const bf16* __restrict__ win2,
    const float* __restrict__ po_mb, const float* __restrict__ po_sb,
    const float* __restrict__ b_in2,
    const float* __restrict__ eps, const float* __restrict__ act,
    const float* __restrict__ in_w1, const float* __restrict__ in_b1,
    float* __restrict__ qm, float* __restrict__ qs,
    float* __restrict__ feat, bf16* __restrict__ x2b, int t) {
  __shared__ float sh[12032];
  // [0,8192): q2 bf16 [16][1024] swizzled; later reused as x1 bf16
  // [8192,9216): hq [16][64] f32 | [9216,9728): zl | [9728,9856): al | [9856,12032): shE 8x272
  const int bid = blockIdx.x, tid = threadIdx.x;
  const int lane = tid & 63, wv = tid >> 6;
  const int l15 = lane & 15, kg = lane >> 4, kq = kg * 8, rq = kg * 4;

  if (bid >= 128) {
    // ---- pr2 role: p2 tile [16m x 256n], 16 waves x 1 frag, K=1024 ----
    const int idx = bid - 128, mt = idx & 15, nc = idx >> 4;
    const int m0 = mt * 16, cb = nc * 256 + wv * 16;
    f32x4 c{0.f, 0.f, 0.f, 0.f};
    const bf16* __restrict__ ap = p1b + (size_t)(m0 + l15) * 1024 + kq;
    const bf16* __restrict__ wp = w_pr2 + (size_t)(cb + l15) * 1024 + kq;
    #pragma unroll 4
    for (int k = 0; k < 1024; k += 32) {
      bf16x8 af = *(const bf16x8*)(ap + k);
      c = MF(af, *(const bf16x8*)(wp + k), c);
    }
    const float bv = b_pr2[cb + l15];
    #pragma unroll
    for (int r = 0; r < 4; ++r) {
      const float v = fmaxf(c[r] + bv, 0.f);
      p2b[(size_t)(m0 + kg * 4 + r) * 1024 + cb + l15] = (bf16)v;
    }
    return;
  }

  const int g = bid >> 3, nt = bid & 7, m0 = g * 16;
  float* hq  = sh + 8192;
  float* zl  = sh + 9216;
  float* al  = sh + 9728;
  float* shE = sh + 9856;
  char* ldsb = (char*)sh;    // q2 / x1 bf16 region (32 KB)

  // ---- Phase Q2: q2[16x1024] = relu(q1 @ po_w2^T + b) -> LDS (swizzled bf16) ----
  {
    const int cw = wv * 64;
    f32x4 c0{0.f,0.f,0.f,0.f}, c1 = c0, c2 = c0, c3 = c0;
    const bf16* __restrict__ ap = q1b + (size_t)(m0 + l15) * 1024 + kq;
    const bf16* __restrict__ wp = w_po2 + (size_t)(cw + l15) * 1024 + kq;
    #pragma unroll 4
    for (int k = 0; k < 1024; k += 32) {
      bf16x8 af = *(const bf16x8*)(ap + k);
      c0 = MF(af, *(const bf16x8*)(wp + k            ), c0);
      c1 = MF(af, *(const bf16x8*)(wp + 16 * 1024 + k), c1);
      c2 = MF(af, *(const bf16x8*)(wp + 32 * 1024 + k), c2);
      c3 = MF(af, *(const bf16x8*)(wp + 48 * 1024 + k), c3);
    }
    f32x4 cc[4] = {c0, c1, c2, c3};
    #pragma unroll
    for (int t2 = 0; t2 < 4; ++t2) {
      const int dcol = cw + t2 * 16 + l15;
      const float bv = b_po2[dcol];
      const int chunk = dcol >> 3, sub = (dcol & 7) * 2;
      #pragma unroll
      for (int r = 0; r < 4; ++r) {
        const int drow = kg * 4 + r;
        const float v = fmaxf(cc[t2][r] + bv, 0.f);
        *(bf16*)(ldsb + drow * 2048 + ((chunk ^ (drow & 7)) << 4) + sub) = (bf16)v;
      }
    }
  }
  if (tid >= 928) {                    // waves 14.5-15: load actions
    const int idx2 = tid - 928;
    if (idx2 < 96) {
      const int r = idx2 / ACT_, k = idx2 - r * ACT_;
      al[r * 8 + k] = act[((size_t)(m0 + r) * T_ + t) * ACT_ + k];
    }
  }
  __syncthreads();

  // ---- Phase H: heads_q [16x64] from LDS q2 (waves 0..3, 1 frag each, K=1024) ----
  if (wv < 4) {
    const int hc = wv * 16;
    f32x4 c{0.f, 0.f, 0.f, 0.f};
    const bf16* __restrict__ wp = whead + (size_t)(64 + hc + l15) * 1024 + kq;  // po half
    #pragma unroll 4
    for (int k = 0; k < 1024; k += 32) {
      const int chunk = (k + kq) >> 3;
      bf16x8 af = *(const bf16x8*)(ldsb + l15 * 2048 + ((chunk ^ (l15 & 7)) << 4));
      c = MF(af, *(const bf16x8*)(wp + k), c);
    }
    #pragma unroll
    for (int r = 0; r < 4; ++r)
      hq[(kg * 4 + r) * 64 + hc + l15] = c[r];
  }
  __syncthreads();

  // ---- Phase B/C: qm/qs/z (writes global only from nt==0) ----
  if (tid < 512) {
    const int r = tid >> 5, j = tid & 31;
    const size_t ob = ((size_t)(m0 + r) * T_ + t) * STO_ + j;
    const float vm = hq[r * 64 + j] + po_mb[j];
    const float vs = __expf(fminf(fmaxf(hq[r * 64 + 32 + j] + po_sb[j], -5.f), 2.f));
    const float z = vm + vs * eps[ob];
    zl[r * 32 + j] = z;
    if (nt == 0) {
      qm[ob] = vm;
      qs[ob] = vs;
      feat[((size_t)(m0 + r) * T_ + t) * 1056 + 1024 + j] = z;
    }
  }
  __syncthreads();

  // ---- Phase D: x1 [16x1024] -> LDS (overwrites q2 region; swizzled bf16) ----
  {
    const int n = tid;
    const float* w = in_w1 + (size_t)n * 38;
    float wreg[38];
    #pragma unroll
    for (int j = 0; j < 38; ++j) wreg[j] = w[j];
    const float bn = in_b1[n];
    const int chunk = n >> 3, sub = (n & 7) * 2;
    #pragma unroll 2
    for (int r = 0; r < 16; ++r) {
      float a = bn;
      #pragma unroll
      for (int k = 0; k < STO_; ++k) a = fmaf(zl[r * 32 + k], wreg[k], a);
      #pragma unroll
      for (int k = 0; k < ACT_; ++k) a = fmaf(al[r * 8 + k], wreg[32 + k], a);
      *(bf16*)(ldsb + r * 2048 + ((chunk ^ (r & 7)) << 4) + sub) = (bf16)fmaxf(a, 0.f);
    }
  }
  __syncthreads();

  // ---- Phase E: x2 tile [16 x 128 at nt*128]; 16 waves = 8 nfrag x 2 ksplit(512) ----
  {
    const int nfrag = wv & 7, kw2 = wv >> 3;
    const int col = nt * 128 + nfrag * 16 + l15;
    f32x4 e0{0.f, 0.f, 0.f, 0.f};
    const bf16* __restrict__ wp = win2 + (size_t)col * 1024 + kw2 * 512 + kq;
    #pragma unroll 4
    for (int k = 0; k < 512; k += 32) {
      const int chunk = (kw2 * 512 + k + kq) >> 3;
      bf16x8 af = *(const bf16x8*)(ldsb + l15 * 2048 + ((chunk ^ (l15 & 7)) << 4));
      e0 = MF(af, *(const bf16x8*)(wp + k), e0);
    }
    if (kw2) {
      float* s = shE + nfrag * 272;
      #pragma unroll
      for (int r = 0; r < 4; ++r) s[(rq + r) * 17 + l15] = e0[r];
    }
    __syncthreads();
    if (kw2 == 0) {
      const float* s = shE + nfrag * 272;
      const float bv = b_in2[col];
      #pragma unroll
      for (int r = 0; r < 4; ++r) {
        const float v = e0[r] + s[(rq + r) * 17 + l15] + bv;
        x2b[(size_t)(m0 + rq + r) * 1024 + col] = (bf16)fmaxf(v, 0.f);
      }
    }
  }
}

extern "C" void kernel_launch(void* const* d_in, const int* in_sizes, int n_in,
                              void* d_out, int out_size, void* d_ws, size_t ws_size,
                              hipStream_t stream) {
  (void)in_sizes; (void)n_in; (void)out_size; (void)ws_size;
  const float* obs      = (const float*)d_in[0];
  const float* actions  = (const float*)d_in[1];
  const float* eps_post = (const float*)d_in[3];   // eps_prior unused by the math
  const float* in_w1 = (const float*)d_in[4];
  const float* in_b1 = (const float*)d_in[5];
  const float* in_w2 = (const float*)d_in[6];
  const float* in_b2 = (const float*)d_in[7];
  const float* gru_wih = (const float*)d_in[8];
  const float* gru_whh = (const float*)d_in[9];
  const float* gru_bih = (const float*)d_in[10];
  const float* gru_bhh = (const float*)d_in[11];
  const float* pr_w1 = (const float*)d_in[12];
  const float* pr_b1 = (const float*)d_in[13];
  const float* pr_w2 = (const float*)d_in[14];
  const float* pr_b2 = (const float*)d_in[15];
  const float* pr_mw = (const float*)d_in[16];
  const float* pr_mb = (const float*)d_in[17];
  const float* pr_sw = (const float*)d_in[18];
  const float* pr_sb = (const float*)d_in[19];
  const float* po_w1 = (const float*)d_in[20];
  const float* po_b1 = (const float*)d_in[21];
  const float* po_w2 = (const float*)d_in[22];
  const float* po_b2 = (const float*)d_in[23];
  const float* po_mw = (const float*)d_in[24];
  const float* po_mb = (const float*)d_in[25];
  const float* po_sw = (const float*)d_in[26];
  const float* po_sb = (const float*)d_in[27];

  float* feat = (float*)d_out;
  float* pm = feat + (size_t)B_ * T_ * 1056;
  float* ps = pm + (size_t)B_ * T_ * STO_;
  float* qm = ps + (size_t)B_ * T_ * STO_;
  float* qs = qm + (size_t)B_ * T_ * STO_;

  char* wp_ = (char*)d_ws;
  auto carve = [&](size_t bytes) -> void* {
    void* r = (void*)wp_;
    wp_ += (bytes + 255) & ~(size_t)255;
    return r;
  };
  bf16* w_in2b  = (bf16*)carve((size_t)HID_ * HID_ * 2);
  bf16* w_wihb  = (bf16*)carve((size_t)3 * HID_ * HID_ * 2);
  bf16* w_whhb  = (bf16*)carve((size_t)3 * HID_ * HID_ * 2);
  bf16* w_pr1b  = (bf16*)carve((size_t)HID_ * HID_ * 2);
  bf16* w_pr2b  = (bf16*)carve((size_t)HID_ * HID_ * 2);
  bf16* w_po1hb = (bf16*)carve((size_t)HID_ * HID_ * 2);
  bf16* w_po1ob = (bf16*)carve((size_t)HID_ * OBS_ * 2);
  bf16* w_po2b  = (bf16*)carve((size_t)HID_ * HID_ * 2);
  bf16* w_headb = (bf16*)carve((size_t)128 * HID_ * 2);
  bf16* obsb    = (bf16*)carve((size_t)B_ * T_ * OBS_ * 2);
  bf16* x1b = (bf16*)carve((size_t)B_ * HID_ * 2);
  bf16* x2b = (bf16*)carve((size_t)B_ * HID_ * 2);
  bf16* hbA = (bf16*)carve((size_t)B_ * HID_ * 2);
  bf16* hbB = (bf16*)carve((size_t)B_ * HID_ * 2);
  bf16* p1b = (bf16*)carve((size_t)B_ * HID_ * 2);
  bf16* q1b = (bf16*)carve((size_t)B_ * HID_ * 2);
  bf16* p2b = (bf16*)carve((size_t)B_ * HID_ * 2);
  float* hfA = (float*)carve((size_t)B_ * HID_ * 4);
  float* hfB = (float*)carve((size_t)B_ * HID_ * 4);

  CvtArgs ca = { in_w2, gru_wih, gru_whh, pr_w1, pr_w2, po_w1, po_w2,
                 pr_mw, pr_sw, po_mw, po_sw, obs,
                 w_in2b, w_wihb, w_whhb, w_pr1b, w_pr2b, w_po1hb, w_po1ob, w_po2b, w_headb, obsb };
  k_cvtall<<<dim3(28800), dim3(256), 0, stream>>>(ca);
  k_init<<<dim3(1024), dim3(256), 0, stream>>>(in_b1, x1b, hbA, hbB, hfA, hfB);

  // x2_0 = relu(x1_0 @ in_w2^T + b2)
  GB2 dummy = {};
  GB2 g_x2i = { x1b, nullptr, w_in2b, nullptr, in_b2, x2b, 1024, 0, 1024, 256 };
  k_l1<<<dim3(256), dim3(256), 0, stream>>>(g_x2i, dummy, 256);

  for (int t = 0; t < T_; ++t) {
    bf16* hbCur = (t & 1) ? hbB : hbA;
    bf16* hbPrev = (t & 1) ? hbA : hbB;
    float* hfCur = (t & 1) ? hfB : hfA;
    float* hfPrev = (t & 1) ? hfA : hfB;

    // L1: gh + gi + gates -> h, feat_h
    k_gru<<<dim3(256), dim3(512), 0, stream>>>(
        hbPrev, hfPrev, hbCur, hfCur, x2b, w_wihb, w_whhb, gru_bih, gru_bhh, feat, t);

    // L2: q1 || pr1 || heads_p(t-1)
    GB2 g_q1  = { hbCur, obsb + (size_t)t * 1024, w_po1hb, w_po1ob, po_b1, q1b,
                  1024, T_ * 1024, 1024, 512 };
    GB2 g_pr1 = { hbCur, nullptr, w_pr1b, nullptr, pr_b1, p1b, 1024, 0, 1024, 256 };
    k_l2<<<dim3(528), dim3(256), 0, stream>>>(
        g_q1, g_pr1, p2b, w_headb, pr_mb, pr_sb, pm, ps, t);

    // L3: fin (q2-in-LDS + heads_q + z + x1 + x2) || pr2
    k_fin4<<<dim3(192), dim3(1024), 0, stream>>>(
        q1b, p1b, w_po2b, po_b2, w_pr2b, pr_b2, p2b,
        w_headb, w_in2b, po_mb, po_sb, in_b2,
        eps_post, actions, in_w1, in_b1, qm, qs, feat, x2b, t);
  }

  // epilogue: heads_p for t = T-1
  k_hp<<<dim3(16), dim3(256), 0, stream>>>(p2b, w_headb, pr_mb, pr_sb, pm, ps);
}

// Round 16
// 5633.862 us; speedup vs baseline: 1.6780x; 1.6780x over previous
//
#include <hip/hip_runtime.h>
#include <hip/hip_bf16.h>

#define B_   256
#define T_   64
#define OBS_ 1024
#define ACT_ 6
#define STO_ 32
#define HID_ 1024

using bf16 = __bf16;
typedef __attribute__((ext_vector_type(8))) __bf16 bf16x8;
typedef __attribute__((ext_vector_type(4))) float f32x4;

__device__ __forceinline__ f32x4 MF(bf16x8 a, bf16x8 b, f32x4 c) {
  return __builtin_amdgcn_mfma_f32_16x16x32_bf16(a, b, c, 0, 0, 0);
}

// ---------------- prologue: weights + obs -> bf16 ----------------
struct CvtArgs {
  const float *in_w2, *gru_wih, *gru_whh, *pr_w1, *pr_w2, *po_w1, *po_w2;
  const float *pr_mw, *pr_sw, *po_mw, *po_sw, *obs;
  bf16 *w_in2b, *w_wihb, *w_whhb, *w_pr1b, *w_pr2b, *w_po1hb, *w_po1ob, *w_po2b, *w_headb, *obsb;
};

__global__ void k_cvtall(CvtArgs a) {
  const int row = blockIdx.x;            // 28800 rows
  const float* src; bf16* dst;
  if      (row < 1024)  { src = a.in_w2   + (size_t)row * 1024;               dst = a.w_in2b  + (size_t)row * 1024; }
  else if (row < 4096)  { int r = row - 1024;  src = a.gru_wih + (size_t)r * 1024;        dst = a.w_wihb  + (size_t)r * 1024; }
  else if (row < 7168)  { int r = row - 4096;  src = a.gru_whh + (size_t)r * 1024;        dst = a.w_whhb  + (size_t)r * 1024; }
  else if (row < 8192)  { int r = row - 7168;  src = a.pr_w1   + (size_t)r * 1024;        dst = a.w_pr1b  + (size_t)r * 1024; }
  else if (row < 9216)  { int r = row - 8192;  src = a.pr_w2   + (size_t)r * 1024;        dst = a.w_pr2b  + (size_t)r * 1024; }
  else if (row < 10240) { int r = row - 9216;  src = a.po_w1   + (size_t)r * 2048;        dst = a.w_po1hb + (size_t)r * 1024; }
  else if (row < 11264) { int r = row - 10240; src = a.po_w1   + (size_t)r * 2048 + 1024; dst = a.w_po1ob + (size_t)r * 1024; }
  else if (row < 12288) { int r = row - 11264; src = a.po_w2   + (size_t)r * 1024;        dst = a.w_po2b  + (size_t)r * 1024; }
  else if (row < 12416) {
    int r = row - 12288;
    const float* hs[4] = { a.pr_mw, a.pr_sw, a.po_mw, a.po_sw };
    src = hs[r >> 5] + (size_t)(r & 31) * 1024;
    dst = a.w_headb + (size_t)r * 1024;
  }
  else { int r = row - 12416; src = a.obs + (size_t)r * 1024; dst = a.obsb + (size_t)r * 1024; }
  const int c = threadIdx.x * 4;
  float4 f = *(const float4*)(src + c);
  dst[c] = (bf16)f.x; dst[c + 1] = (bf16)f.y; dst[c + 2] = (bf16)f.z; dst[c + 3] = (bf16)f.w;
}

__global__ void k_init(const float* __restrict__ in_b1, bf16* __restrict__ x1b,
                       bf16* __restrict__ hbA, bf16* __restrict__ hbB,
                       float* __restrict__ hfA, float* __restrict__ hfB) {
  const int i = blockIdx.x * 256 + threadIdx.x;      // < 262144
  x1b[i] = (bf16)fmaxf(in_b1[i & 1023], 0.f);        // z0=0, a0=0
  hbA[i] = (bf16)0.f; hbB[i] = (bf16)0.f;
  hfA[i] = 0.f; hfB[i] = 0.f;
}

// ---------------- split-K dual-GEMM, two K-segments, bf16 out ----------------
// tile 16m x 64n; 4 waves K-split (kseg each); LDS reduce; relu; out bf16 ld 1024.
// XCD-locality: n-tile = tile&15 so all m-blocks of one n-slice share one XCD L2.
struct GB2 {
  const bf16 *A1, *A2, *W1, *W2;
  const float* bias;
  bf16* out;
  int lda1, lda2, K1, kseg;
};

__global__ __launch_bounds__(256, 4) void k_l1(GB2 g0, GB2 g1, int s1) {
  GB2 g; int tile;
  if ((int)blockIdx.x < s1) { g = g0; tile = blockIdx.x; }
  else                      { g = g1; tile = blockIdx.x - s1; }
  __shared__ float sh[3 * 1056];
  const int tid = threadIdx.x, lane = tid & 63, kw = tid >> 6;
  const int l15 = lane & 15, kg = lane >> 4, kq = kg * 8, rq = kg * 4;
  const int m0 = (tile >> 4) * 16, n0 = (tile & 15) * 64;   // XCD swizzle (was m=&15,n=>>4)
  const int kb = kw * g.kseg;

  const bf16* __restrict__ ap;
  const bf16* __restrict__ wp;
  if (kb < g.K1) {
    ap = g.A1 + (size_t)(m0 + l15) * g.lda1 + kb + kq;
    wp = g.W1 + (size_t)(n0 + l15) * 1024 + kb + kq;
  } else {
    ap = g.A2 + (size_t)(m0 + l15) * g.lda2 + (kb - g.K1) + kq;
    wp = g.W2 + (size_t)(n0 + l15) * 1024 + (kb - g.K1) + kq;
  }
  f32x4 c0{0.f,0.f,0.f,0.f}, c1 = c0, c2 = c0, c3 = c0;
  #pragma unroll 8
  for (int k = 0; k < g.kseg; k += 32) {
    bf16x8 af = *(const bf16x8*)(ap + k);
    c0 = MF(af, *(const bf16x8*)(wp + k            ), c0);
    c1 = MF(af, *(const bf16x8*)(wp + 16 * 1024 + k), c1);
    c2 = MF(af, *(const bf16x8*)(wp + 32 * 1024 + k), c2);
    c3 = MF(af, *(const bf16x8*)(wp + 48 * 1024 + k), c3);
  }
  f32x4 cc[4] = {c0, c1, c2, c3};
  if (kw) {
    float* s = sh + (kw - 1) * 1056;
    #pragma unroll
    for (int t2 = 0; t2 < 4; ++t2)
      #pragma unroll
      for (int r = 0; r < 4; ++r)
        s[(rq + r) * 66 + t2 * 16 + l15] = cc[t2][r];
  }
  __syncthreads();
  if (kw == 0) {
    #pragma unroll
    for (int t2 = 0; t2 < 4; ++t2) {
      const int n = n0 + t2 * 16 + l15;
      const float bv = g.bias[n];
      #pragma unroll
      for (int r = 0; r < 4; ++r) {
        float v = cc[t2][r] + bv;
        #pragma unroll
        for (int s = 0; s < 3; ++s)
          v += sh[s * 1056 + (rq + r) * 66 + t2 * 16 + l15];
        g.out[(size_t)(m0 + rq + r) * 1024 + n] = (bf16)fmaxf(v, 0.f);
      }
    }
  }
}

// ---------------- gh + gi + GRU gates fused (R12-verified numerics) ----------------
// XCD-locality: cs = bid&63 so the 4 m-blocks of one gate-col slice share one XCD L2.
__global__ __launch_bounds__(512, 2) void k_gru(
    const bf16* __restrict__ hbPrev, const float* __restrict__ hfPrev,
    bf16* __restrict__ hbCur, float* __restrict__ hfCur,
    const bf16* __restrict__ x2b, const bf16* __restrict__ wih,
    const bf16* __restrict__ whh, const float* __restrict__ bih,
    const float* __restrict__ bhh, float* __restrict__ feat, int t) {
  __shared__ float sh[4 * 1088];
  const int mt = blockIdx.x >> 6, cs = blockIdx.x & 63;     // XCD swizzle (was mt=&3,cs=>>2)
  const int tid = threadIdx.x, lane = tid & 63, wv = tid >> 6;
  const int msub = wv & 3, kw = wv >> 2;
  const int l15 = lane & 15, kg = lane >> 4, kq = kg * 8, rq = kg * 4;
  const int mrow = mt * 64 + msub * 16;
  const int c0 = cs * 16;
  const int kb = kw * 512;
  const size_t GOFF = (size_t)1024 * 1024;

  f32x4 ghR{0.f,0.f,0.f,0.f}, ghZ = ghR, ghN = ghR, giR = ghR, giZ = ghR, giN = ghR;
  {
    const bf16* __restrict__ ap = hbPrev + (size_t)(mrow + l15) * 1024 + kb + kq;
    const bf16* __restrict__ wr = whh + (size_t)(c0 + l15) * 1024 + kb + kq;
    #pragma unroll 4
    for (int k = 0; k < 512; k += 32) {
      bf16x8 af = *(const bf16x8*)(ap + k);
      ghR = MF(af, *(const bf16x8*)(wr + k           ), ghR);
      ghZ = MF(af, *(const bf16x8*)(wr + GOFF + k    ), ghZ);
      ghN = MF(af, *(const bf16x8*)(wr + 2 * GOFF + k), ghN);
    }
  }
  {
    const bf16* __restrict__ ap = x2b + (size_t)(mrow + l15) * 1024 + kb + kq;
    const bf16* __restrict__ wr = wih + (size_t)(c0 + l15) * 1024 + kb + kq;
    #pragma unroll 4
    for (int k = 0; k < 512; k += 32) {
      bf16x8 af = *(const bf16x8*)(ap + k);
      giR = MF(af, *(const bf16x8*)(wr + k           ), giR);
      giZ = MF(af, *(const bf16x8*)(wr + GOFF + k    ), giZ);
      giN = MF(af, *(const bf16x8*)(wr + 2 * GOFF + k), giN);
    }
  }
  f32x4 sR = ghR + giR, sZ = ghZ + giZ;
  if (kw) {
    float* s = sh + msub * 1088;
    #pragma unroll
    for (int r = 0; r < 4; ++r) {
      s[      (rq + r) * 17 + l15] = sR[r];
      s[272 + (rq + r) * 17 + l15] = sZ[r];
      s[544 + (rq + r) * 17 + l15] = giN[r];
      s[816 + (rq + r) * 17 + l15] = ghN[r];
    }
  }
  __syncthreads();
  if (kw == 0) {
    const int c = c0 + l15;
    const float bir = bih[c], biz = bih[1024 + c], bin_ = bih[2048 + c];
    const float bhr = bhh[c], bhz = bhh[1024 + c], bhn = bhh[2048 + c];
    const float* s = sh + msub * 1088;
    #pragma unroll
    for (int r = 0; r < 4; ++r) {
      const float vr  = sR[r]  + s[      (rq + r) * 17 + l15];
      const float vz  = sZ[r]  + s[272 + (rq + r) * 17 + l15];
      const float vin = giN[r] + s[544 + (rq + r) * 17 + l15];
      const float vhn = ghN[r] + s[816 + (rq + r) * 17 + l15];
      const int row = mrow + rq + r;
      float rr = vr + bir + bhr;
      float zz = vz + biz + bhz;
      rr = 1.f / (1.f + __expf(-rr));
      zz = 1.f / (1.f + __expf(-zz));
      const float nn = tanhf(vin + bin_ + rr * (vhn + bhn));
      const float h2 = (1.f - zz) * nn + zz * hfPrev[(size_t)row * 1024 + c];
      hbCur[(size_t)row * 1024 + c] = (bf16)h2;
      hfCur[(size_t)row * 1024 + c] = h2;
      feat[((size_t)row * T_ + t) * 1056 + c] = h2;
    }
  }
}

// ---------------- heads + stats + z + feat_z + x1(LDS) + next x2 (WIDE, R14-verified) ----------------
// 128 blocks = 16 row-groups (g=bid>>3) x 8 x2-col-tiles (nt=bid&7 -> XCD=nt, already local).
__global__ __launch_bounds__(1024, 1) void k_fin3(
    const bf16* __restrict__ p2b, const bf16* __restrict__ q2b,
    const bf16* __restrict__ whead, const bf16* __restrict__ win2,
    const float* __restrict__ pr_mb, const float* __restrict__ pr_sb,
    const float* __restrict__ po_mb, const float* __restrict__ po_sb,
    const float* __restrict__ b_in2,
    const float* __restrict__ eps, const float* __restrict__ act,
    const float* __restrict__ in_w1, const float* __restrict__ in_b1,
    float* __restrict__ pm, float* __restrict__ ps,
    float* __restrict__ qm, float* __restrict__ qs,
    float* __restrict__ feat, bf16* __restrict__ x2b, int t) {
  __shared__ float sh[12288];
  const int g = blockIdx.x >> 3, nt = blockIdx.x & 7, m0 = g * 16;
  const int tid = threadIdx.x, lane = tid & 63, wv = tid >> 6;
  const int l15 = lane & 15, kg = lane >> 4, kq = kg * 8, rq = kg * 4;
  float* zm = sh + 8448;
  float* zs = sh + 8960;
  float* zl = sh + 9472;
  float* al = sh + 9984;
  float* shE = sh + 10112;

  if (wv < 8) {
    const int kw = wv & 3, half = wv >> 2;
    const bf16* __restrict__ A = half ? q2b : p2b;
    f32x4 c0{0.f,0.f,0.f,0.f}, c1 = c0, c2 = c0, c3 = c0;
    const bf16* __restrict__ ap = A + (size_t)(m0 + l15) * 1024 + kw * 256 + kq;
    const bf16* __restrict__ wp = whead + (size_t)(half * 64 + l15) * 1024 + kw * 256 + kq;
    #pragma unroll
    for (int k = 0; k < 256; k += 32) {
      bf16x8 af = *(const bf16x8*)(ap + k);
      c0 = MF(af, *(const bf16x8*)(wp + k            ), c0);
      c1 = MF(af, *(const bf16x8*)(wp + 16 * 1024 + k), c1);
      c2 = MF(af, *(const bf16x8*)(wp + 32 * 1024 + k), c2);
      c3 = MF(af, *(const bf16x8*)(wp + 48 * 1024 + k), c3);
    }
    f32x4 cc[4] = {c0, c1, c2, c3};
    float* s = sh + wv * 1056;
    #pragma unroll
    for (int t2 = 0; t2 < 4; ++t2)
      #pragma unroll
      for (int r = 0; r < 4; ++r)
        s[(rq + r) * 66 + t2 * 16 + l15] = cc[t2][r];
  }
  if (tid >= 928 && tid < 1024) {
    const int idx = tid - 928, r = idx / ACT_, k = idx - r * ACT_;
    al[r * 8 + k] = act[((size_t)(m0 + r) * T_ + t) * ACT_ + k];
  }
  __syncthreads();

  #pragma unroll
  for (int rep = 0; rep < 2; ++rep) {
    const int idx = rep * 1024 + tid;
    const int r = idx >> 7, c = idx & 127;
    const int base = (c < 64) ? 0 : 4, cl = c & 63, j = c & 31;
    float v = sh[base * 1056 + r * 66 + cl] + sh[(base + 1) * 1056 + r * 66 + cl]
            + sh[(base + 2) * 1056 + r * 66 + cl] + sh[(base + 3) * 1056 + r * 66 + cl];
    const size_t ob = ((size_t)(m0 + r) * T_ + t) * STO_ + j;
    const int sel = c >> 5;
    if (sel == 0) {
      if (nt == 0) pm[ob] = v + pr_mb[j];
    } else if (sel == 1) {
      if (nt == 0) ps[ob] = __expf(fminf(fmaxf(v + pr_sb[j], -5.f), 2.f));
    } else if (sel == 2) {
      const float x = v + po_mb[j];
      if (nt == 0) qm[ob] = x;
      zm[r * 32 + j] = x;
    } else {
      const float x = __expf(fminf(fmaxf(v + po_sb[j], -5.f), 2.f));
      if (nt == 0) qs[ob] = x;
      zs[r * 32 + j] = x;
    }
  }
  __syncthreads();

  if (tid < 512) {
    const int r = tid >> 5, j = tid & 31;
    const float z = zm[r * 32 + j] + zs[r * 32 + j] * eps[((size_t)(m0 + r) * T_ + t) * STO_ + j];
    zl[r * 32 + j] = z;
    if (nt == 0) feat[((size_t)(m0 + r) * T_ + t) * 1056 + 1024 + j] = z;
  }
  __syncthreads();

  {
    char* x1c = (char*)sh;
    const int n = tid;
    const float* w = in_w1 + (size_t)n * 38;
    float wreg[38];
    #pragma unroll
    for (int j = 0; j < 38; ++j) wreg[j] = w[j];
    const float bn = in_b1[n];
    const int chunk = n >> 3, sub = (n & 7) * 2;
    #pragma unroll 2
    for (int r = 0; r < 16; ++r) {
      float a = bn;
      #pragma unroll
      for (int k = 0; k < STO_; ++k) a = fmaf(zl[r * 32 + k], wreg[k], a);
      #pragma unroll
      for (int k = 0; k < ACT_; ++k) a = fmaf(al[r * 8 + k], wreg[32 + k], a);
      *(bf16*)(x1c + r * 2048 + ((chunk ^ (r & 7)) << 4) + sub) = (bf16)fmaxf(a, 0.f);
    }
  }
  __syncthreads();

  {
    const char* x1c = (const char*)sh;
    const int nfrag = wv & 7, kw2 = wv >> 3;
    const int col = nt * 128 + nfrag * 16 + l15;
    f32x4 e0{0.f,0.f,0.f,0.f};
    const bf16* __restrict__ wp = win2 + (size_t)col * 1024 + kw2 * 512 + kq;
    #pragma unroll 4
    for (int k = 0; k < 512; k += 32) {
      const int chunk = (kw2 * 512 + k + kq) >> 3;
      bf16x8 af = *(const bf16x8*)(x1c + l15 * 2048 + ((chunk ^ (l15 & 7)) << 4));
      e0 = MF(af, *(const bf16x8*)(wp + k), e0);
    }
    if (kw2) {
      float* s = shE + nfrag * 272;
      #pragma unroll
      for (int r = 0; r < 4; ++r) s[(rq + r) * 17 + l15] = e0[r];
    }
    __syncthreads();
    if (kw2 == 0) {
      const float* s = shE + nfrag * 272;
      const float bv = b_in2[col];
      #pragma unroll
      for (int r = 0; r < 4; ++r) {
        const float v = e0[r] + s[(rq + r) * 17 + l15] + bv;
        x2b[(size_t)(m0 + rq + r) * 1024 + col] = (bf16)fmaxf(v, 0.f);
      }
    }
  }
}

extern "C" void kernel_launch(void* const* d_in, const int* in_sizes, int n_in,
                              void* d_out, int out_size, void* d_ws, size_t ws_size,
                              hipStream_t stream) {
  (void)in_sizes; (void)n_in; (void)out_size; (void)ws_size;
  const float* obs      = (const float*)d_in[0];
  const float* actions  = (const float*)d_in[1];
  const float* eps_post = (const float*)d_in[3];   // eps_prior unused by the math
  const float* in_w1 = (const float*)d_in[4];
  const float* in_b1 = (const float*)d_in[5];
  const float* in_w2 = (const float*)d_in[6];
  const float* in_b2 = (const float*)d_in[7];
  const float* gru_wih = (const float*)d_in[8];
  const float* gru_whh = (const float*)d_in[9];
  const float* gru_bih = (const float*)d_in[10];
  const float* gru_bhh = (const float*)d_in[11];
  const float* pr_w1 = (const float*)d_in[12];
  const float* pr_b1 = (const float*)d_in[13];
  const float* pr_w2 = (const float*)d_in[14];
  const float* pr_b2 = (const float*)d_in[15];
  const float* pr_mw = (const float*)d_in[16];
  const float* pr_mb = (const float*)d_in[17];
  const float* pr_sw = (const float*)d_in[18];
  const float* pr_sb = (const float*)d_in[19];
  const float* po_w1 = (const float*)d_in[20];
  const float* po_b1 = (const float*)d_in[21];
  const float* po_w2 = (const float*)d_in[22];
  const float* po_b2 = (const float*)d_in[23];
  const float* po_mw = (const float*)d_in[24];
  const float* po_mb = (const float*)d_in[25];
  const float* po_sw = (const float*)d_in[26];
  const float* po_sb = (const float*)d_in[27];

  float* feat = (float*)d_out;
  float* pm = feat + (size_t)B_ * T_ * 1056;
  float* ps = pm + (size_t)B_ * T_ * STO_;
  float* qm = ps + (size_t)B_ * T_ * STO_;
  float* qs = qm + (size_t)B_ * T_ * STO_;

  char* wp_ = (char*)d_ws;
  auto carve = [&](size_t bytes) -> void* {
    void* r = (void*)wp_;
    wp_ += (bytes + 255) & ~(size_t)255;
    return r;
  };
  bf16* w_in2b  = (bf16*)carve((size_t)HID_ * HID_ * 2);
  bf16* w_wihb  = (bf16*)carve((size_t)3 * HID_ * HID_ * 2);
  bf16* w_whhb  = (bf16*)carve((size_t)3 * HID_ * HID_ * 2);
  bf16* w_pr1b  = (bf16*)carve((size_t)HID_ * HID_ * 2);
  bf16* w_pr2b  = (bf16*)carve((size_t)HID_ * HID_ * 2);
  bf16* w_po1hb = (bf16*)carve((size_t)HID_ * HID_ * 2);
  bf16* w_po1ob = (bf16*)carve((size_t)HID_ * OBS_ * 2);
  bf16* w_po2b  = (bf16*)carve((size_t)HID_ * HID_ * 2);
  bf16* w_headb = (bf16*)carve((size_t)128 * HID_ * 2);
  bf16* obsb    = (bf16*)carve((size_t)B_ * T_ * OBS_ * 2);
  bf16* x1b = (bf16*)carve((size_t)B_ * HID_ * 2);
  bf16* x2b = (bf16*)carve((size_t)B_ * HID_ * 2);
  bf16* hbA = (bf16*)carve((size_t)B_ * HID_ * 2);
  bf16* hbB = (bf16*)carve((size_t)B_ * HID_ * 2);
  bf16* p1b = (bf16*)carve((size_t)B_ * HID_ * 2);
  bf16* q1b = (bf16*)carve((size_t)B_ * HID_ * 2);
  bf16* p2b = (bf16*)carve((size_t)B_ * HID_ * 2);
  bf16* q2b = (bf16*)carve((size_t)B_ * HID_ * 2);
  float* hfA = (float*)carve((size_t)B_ * HID_ * 4);
  float* hfB = (float*)carve((size_t)B_ * HID_ * 4);

  CvtArgs ca = { in_w2, gru_wih, gru_whh, pr_w1, pr_w2, po_w1, po_w2,
                 pr_mw, pr_sw, po_mw, po_sw, obs,
                 w_in2b, w_wihb, w_whhb, w_pr1b, w_pr2b, w_po1hb, w_po1ob, w_po2b, w_headb, obsb };
  k_cvtall<<<dim3(28800), dim3(256), 0, stream>>>(ca);
  k_init<<<dim3(1024), dim3(256), 0, stream>>>(in_b1, x1b, hbA, hbB, hfA, hfB);

  // x2_0 = relu(x1_0 @ in_w2^T + b2)
  GB2 dummy = {};
  GB2 g_x2i = { x1b, nullptr, w_in2b, nullptr, in_b2, x2b, 1024, 0, 1024, 256 };
  k_l1<<<dim3(256), dim3(256), 0, stream>>>(g_x2i, dummy, 256);

  for (int t = 0; t < T_; ++t) {
    bf16* hbCur = (t & 1) ? hbB : hbA;
    bf16* hbPrev = (t & 1) ? hbA : hbB;
    float* hfCur = (t & 1) ? hfB : hfA;
    float* hfPrev = (t & 1) ? hfA : hfB;

    // K1: gh + gi + gates -> h, feat_h
    k_gru<<<dim3(256), dim3(512), 0, stream>>>(
        hbPrev, hfPrev, hbCur, hfCur, x2b, w_wihb, w_whhb, gru_bih, gru_bhh, feat, t);

    // K2: pr1 (K=1024) || q1 (K=2048: h-part + obs-part)
    GB2 g_pr1 = { hbCur, nullptr, w_pr1b, nullptr, pr_b1, p1b, 1024, 0, 1024, 256 };
    GB2 g_q1  = { hbCur, obsb + (size_t)t * 1024, w_po1hb, w_po1ob, po_b1, q1b,
                  1024, T_ * 1024, 1024, 512 };
    k_l1<<<dim3(512), dim3(256), 0, stream>>>(g_pr1, g_q1, 256);

    // K3: pr2 || po2
    GB2 g_pr2 = { p1b, nullptr, w_pr2b, nullptr, pr_b2, p2b, 1024, 0, 1024, 256 };
    GB2 g_po2 = { q1b, nullptr, w_po2b, nullptr, po_b2, q2b, 1024, 0, 1024, 256 };
    k_l1<<<dim3(512), dim3(256), 0, stream>>>(g_pr2, g_po2, 256);

    // K4: heads + stats + z + feat_z + x1(LDS) + next x2 (wide)
    k_fin3<<<dim3(128), dim3(1024), 0, stream>>>(
        p2b, q2b, w_headb, w_in2b, pr_mb, pr_sb, po_mb, po_sb, in_b2,
        eps_post, actions, in_w1, in_b1, pm, ps, qm, qs, feat, x2b, t);
  }
}

// Round 17
// 5581.617 us; speedup vs baseline: 1.6937x; 1.0094x over previous
//
#include <hip/hip_runtime.h>
#include <hip/hip_bf16.h>

#define B_   256
#define T_   64
#define OBS_ 1024
#define ACT_ 6
#define STO_ 32
#define HID_ 1024

using bf16 = __bf16;
typedef __attribute__((ext_vector_type(8))) __bf16 bf16x8;
typedef __attribute__((ext_vector_type(4))) float f32x4;

__device__ __forceinline__ f32x4 MF(bf16x8 a, bf16x8 b, f32x4 c) {
  return __builtin_amdgcn_mfma_f32_16x16x32_bf16(a, b, c, 0, 0, 0);
}

// ---------------- prologue: weights + obs -> bf16 ----------------
struct CvtArgs {
  const float *in_w2, *gru_wih, *gru_whh, *pr_w1, *pr_w2, *po_w1, *po_w2;
  const float *pr_mw, *pr_sw, *po_mw, *po_sw, *obs;
  bf16 *w_in2b, *w_wihb, *w_whhb, *w_pr1b, *w_pr2b, *w_po1hb, *w_po1ob, *w_po2b, *w_headb, *obsb;
};

__global__ void k_cvtall(CvtArgs a) {
  const int row = blockIdx.x;            // 28800 rows
  const float* src; bf16* dst;
  if      (row < 1024)  { src = a.in_w2   + (size_t)row * 1024;               dst = a.w_in2b  + (size_t)row * 1024; }
  else if (row < 4096)  { int r = row - 1024;  src = a.gru_wih + (size_t)r * 1024;        dst = a.w_wihb  + (size_t)r * 1024; }
  else if (row < 7168)  { int r = row - 4096;  src = a.gru_whh + (size_t)r * 1024;        dst = a.w_whhb  + (size_t)r * 1024; }
  else if (row < 8192)  { int r = row - 7168;  src = a.pr_w1   + (size_t)r * 1024;        dst = a.w_pr1b  + (size_t)r * 1024; }
  else if (row < 9216)  { int r = row - 8192;  src = a.pr_w2   + (size_t)r * 1024;        dst = a.w_pr2b  + (size_t)r * 1024; }
  else if (row < 10240) { int r = row - 9216;  src = a.po_w1   + (size_t)r * 2048;        dst = a.w_po1hb + (size_t)r * 1024; }
  else if (row < 11264) { int r = row - 10240; src = a.po_w1   + (size_t)r * 2048 + 1024; dst = a.w_po1ob + (size_t)r * 1024; }
  else if (row < 12288) { int r = row - 11264; src = a.po_w2   + (size_t)r * 1024;        dst = a.w_po2b  + (size_t)r * 1024; }
  else if (row < 12416) {
    int r = row - 12288;
    const float* hs[4] = { a.pr_mw, a.pr_sw, a.po_mw, a.po_sw };
    src = hs[r >> 5] + (size_t)(r & 31) * 1024;
    dst = a.w_headb + (size_t)r * 1024;
  }
  else { int r = row - 12416; src = a.obs + (size_t)r * 1024; dst = a.obsb + (size_t)r * 1024; }
  const int c = threadIdx.x * 4;
  float4 f = *(const float4*)(src + c);
  dst[c] = (bf16)f.x; dst[c + 1] = (bf16)f.y; dst[c + 2] = (bf16)f.z; dst[c + 3] = (bf16)f.w;
}

__global__ void k_init(const float* __restrict__ in_b1, bf16* __restrict__ x1b,
                       bf16* __restrict__ hbA, bf16* __restrict__ hbB,
                       float* __restrict__ hfA, float* __restrict__ hfB) {
  const int i = blockIdx.x * 256 + threadIdx.x;      // < 262144
  x1b[i] = (bf16)fmaxf(in_b1[i & 1023], 0.f);        // z0=0, a0=0
  hbA[i] = (bf16)0.f; hbB[i] = (bf16)0.f;
  hfA[i] = 0.f; hfB[i] = 0.f;
}

// ---------------- split-K dual-GEMM, 8 waves, two K-segments, bf16 out ----------------
// tile 16m x 64n; 8 waves K-split (kseg each); LDS reduce; relu; out bf16 ld 1024.
// XCD-locality: n-slice = tile&15 -> all m-blocks of one n-slice share one XCD L2.
struct GB2 {
  const bf16 *A1, *A2, *W1, *W2;
  const float* bias;
  bf16* out;
  int lda1, lda2, K1, kseg;
};

__global__ __launch_bounds__(512, 2) void k_l1(GB2 g0, GB2 g1, int s1) {
  GB2 g; int tile;
  if ((int)blockIdx.x < s1) { g = g0; tile = blockIdx.x; }
  else                      { g = g1; tile = blockIdx.x - s1; }
  __shared__ float sh[7 * 1056];
  const int tid = threadIdx.x, lane = tid & 63, kw = tid >> 6;   // kw 0..7
  const int l15 = lane & 15, kg = lane >> 4, kq = kg * 8, rq = kg * 4;
  const int m0 = (tile >> 4) * 16, n0 = (tile & 15) * 64;
  const int kb = kw * g.kseg;

  const bf16* __restrict__ ap;
  const bf16* __restrict__ wp;
  if (kb < g.K1) {
    ap = g.A1 + (size_t)(m0 + l15) * g.lda1 + kb + kq;
    wp = g.W1 + (size_t)(n0 + l15) * 1024 + kb + kq;
  } else {
    ap = g.A2 + (size_t)(m0 + l15) * g.lda2 + (kb - g.K1) + kq;
    wp = g.W2 + (size_t)(n0 + l15) * 1024 + (kb - g.K1) + kq;
  }
  f32x4 c0{0.f,0.f,0.f,0.f}, c1 = c0, c2 = c0, c3 = c0;
  #pragma unroll 8
  for (int k = 0; k < g.kseg; k += 32) {
    bf16x8 af = *(const bf16x8*)(ap + k);
    c0 = MF(af, *(const bf16x8*)(wp + k            ), c0);
    c1 = MF(af, *(const bf16x8*)(wp + 16 * 1024 + k), c1);
    c2 = MF(af, *(const bf16x8*)(wp + 32 * 1024 + k), c2);
    c3 = MF(af, *(const bf16x8*)(wp + 48 * 1024 + k), c3);
  }
  f32x4 cc[4] = {c0, c1, c2, c3};
  if (kw) {
    float* s = sh + (kw - 1) * 1056;
    #pragma unroll
    for (int t2 = 0; t2 < 4; ++t2)
      #pragma unroll
      for (int r = 0; r < 4; ++r)
        s[(rq + r) * 66 + t2 * 16 + l15] = cc[t2][r];
  }
  __syncthreads();
  if (kw == 0) {
    #pragma unroll
    for (int t2 = 0; t2 < 4; ++t2) {
      const int n = n0 + t2 * 16 + l15;
      const float bv = g.bias[n];
      #pragma unroll
      for (int r = 0; r < 4; ++r) {
        float v = cc[t2][r] + bv;
        #pragma unroll
        for (int s = 0; s < 7; ++s)
          v += sh[s * 1056 + (rq + r) * 66 + t2 * 16 + l15];
        g.out[(size_t)(m0 + rq + r) * 1024 + n] = (bf16)fmaxf(v, 0.f);
      }
    }
  }
}

// ---------------- gh + gi + GRU gates fused (R12-verified numerics, 8mt x 64cs) ----------------
// 512 blocks: mt = bid>>6 (0..7, 32 rows), cs = bid&63 (16 gate-cols; XCD = cs%8).
// 8 waves = 2 msub x 4 kw; kseg 256.
__global__ __launch_bounds__(512, 2) void k_gru(
    const bf16* __restrict__ hbPrev, const float* __restrict__ hfPrev,
    bf16* __restrict__ hbCur, float* __restrict__ hfCur,
    const bf16* __restrict__ x2b, const bf16* __restrict__ wih,
    const bf16* __restrict__ whh, const float* __restrict__ bih,
    const float* __restrict__ bhh, float* __restrict__ feat, int t) {
  __shared__ float sh[6 * 1088];     // [msub][kw-1] x 4 quantities x 16 x 17
  const int mt = blockIdx.x >> 6, cs = blockIdx.x & 63;
  const int tid = threadIdx.x, lane = tid & 63, wv = tid >> 6;
  const int msub = wv & 1, kw = wv >> 1;          // msub 0..1, kw 0..3
  const int l15 = lane & 15, kg = lane >> 4, kq = kg * 8, rq = kg * 4;
  const int mrow = mt * 32 + msub * 16;
  const int c0 = cs * 16;
  const int kb = kw * 256;
  const size_t GOFF = (size_t)1024 * 1024;

  f32x4 ghR{0.f,0.f,0.f,0.f}, ghZ = ghR, ghN = ghR, giR = ghR, giZ = ghR, giN = ghR;
  {
    const bf16* __restrict__ ap = hbPrev + (size_t)(mrow + l15) * 1024 + kb + kq;
    const bf16* __restrict__ wr = whh + (size_t)(c0 + l15) * 1024 + kb + kq;
    #pragma unroll 4
    for (int k = 0; k < 256; k += 32) {
      bf16x8 af = *(const bf16x8*)(ap + k);
      ghR = MF(af, *(const bf16x8*)(wr + k           ), ghR);
      ghZ = MF(af, *(const bf16x8*)(wr + GOFF + k    ), ghZ);
      ghN = MF(af, *(const bf16x8*)(wr + 2 * GOFF + k), ghN);
    }
  }
  {
    const bf16* __restrict__ ap = x2b + (size_t)(mrow + l15) * 1024 + kb + kq;
    const bf16* __restrict__ wr = wih + (size_t)(c0 + l15) * 1024 + kb + kq;
    #pragma unroll 4
    for (int k = 0; k < 256; k += 32) {
      bf16x8 af = *(const bf16x8*)(ap + k);
      giR = MF(af, *(const bf16x8*)(wr + k           ), giR);
      giZ = MF(af, *(const bf16x8*)(wr + GOFF + k    ), giZ);
      giN = MF(af, *(const bf16x8*)(wr + 2 * GOFF + k), giN);
    }
  }
  f32x4 sR = ghR + giR, sZ = ghZ + giZ;
  if (kw) {
    float* s = sh + (msub * 3 + (kw - 1)) * 1088;
    #pragma unroll
    for (int r = 0; r < 4; ++r) {
      s[      (rq + r) * 17 + l15] = sR[r];
      s[272 + (rq + r) * 17 + l15] = sZ[r];
      s[544 + (rq + r) * 17 + l15] = giN[r];
      s[816 + (rq + r) * 17 + l15] = ghN[r];
    }
  }
  __syncthreads();
  if (kw == 0) {
    const int c = c0 + l15;
    const float bir = bih[c], biz = bih[1024 + c], bin_ = bih[2048 + c];
    const float bhr = bhh[c], bhz = bhh[1024 + c], bhn = bhh[2048 + c];
    #pragma unroll
    for (int r = 0; r < 4; ++r) {
      float vr = sR[r], vz = sZ[r], vin = giN[r], vhn = ghN[r];
      #pragma unroll
      for (int sidx = 0; sidx < 3; ++sidx) {
        const float* s = sh + (msub * 3 + sidx) * 1088;
        vr  += s[      (rq + r) * 17 + l15];
        vz  += s[272 + (rq + r) * 17 + l15];
        vin += s[544 + (rq + r) * 17 + l15];
        vhn += s[816 + (rq + r) * 17 + l15];
      }
      const int row = mrow + rq + r;
      float rr = vr + bir + bhr;
      float zz = vz + biz + bhz;
      rr = 1.f / (1.f + __expf(-rr));
      zz = 1.f / (1.f + __expf(-zz));
      const float nn = tanhf(vin + bin_ + rr * (vhn + bhn));
      const float h2 = (1.f - zz) * nn + zz * hfPrev[(size_t)row * 1024 + c];
      hbCur[(size_t)row * 1024 + c] = (bf16)h2;
      hfCur[(size_t)row * 1024 + c] = h2;
      feat[((size_t)row * T_ + t) * 1056 + c] = h2;
    }
  }
}

// ---------------- heads + stats + z + feat_z + x1(LDS) + next x2 (WIDE, R14-verified) ----------------
__global__ __launch_bounds__(1024, 1) void k_fin3(
    const bf16* __restrict__ p2b, const bf16* __restrict__ q2b,
    const bf16* __restrict__ whead, const bf16* __restrict__ win2,
    const float* __restrict__ pr_mb, const float* __restrict__ pr_sb,
    const float* __restrict__ po_mb, const float* __restrict__ po_sb,
    const float* __restrict__ b_in2,
    const float* __restrict__ eps, const float* __restrict__ act,
    const float* __restrict__ in_w1, const float* __restrict__ in_b1,
    float* __restrict__ pm, float* __restrict__ ps,
    float* __restrict__ qm, float* __restrict__ qs,
    float* __restrict__ feat, bf16* __restrict__ x2b, int t) {
  __shared__ float sh[12288];
  const int g = blockIdx.x >> 3, nt = blockIdx.x & 7, m0 = g * 16;
  const int tid = threadIdx.x, lane = tid & 63, wv = tid >> 6;
  const int l15 = lane & 15, kg = lane >> 4, kq = kg * 8, rq = kg * 4;
  float* zm = sh + 8448;
  float* zs = sh + 8960;
  float* zl = sh + 9472;
  float* al = sh + 9984;
  float* shE = sh + 10112;

  if (wv < 8) {
    const int kw = wv & 3, half = wv >> 2;
    const bf16* __restrict__ A = half ? q2b : p2b;
    f32x4 c0{0.f,0.f,0.f,0.f}, c1 = c0, c2 = c0, c3 = c0;
    const bf16* __restrict__ ap = A + (size_t)(m0 + l15) * 1024 + kw * 256 + kq;
    const bf16* __restrict__ wp = whead + (size_t)(half * 64 + l15) * 1024 + kw * 256 + kq;
    #pragma unroll
    for (int k = 0; k < 256; k += 32) {
      bf16x8 af = *(const bf16x8*)(ap + k);
      c0 = MF(af, *(const bf16x8*)(wp + k            ), c0);
      c1 = MF(af, *(const bf16x8*)(wp + 16 * 1024 + k), c1);
      c2 = MF(af, *(const bf16x8*)(wp + 32 * 1024 + k), c2);
      c3 = MF(af, *(const bf16x8*)(wp + 48 * 1024 + k), c3);
    }
    f32x4 cc[4] = {c0, c1, c2, c3};
    float* s = sh + wv * 1056;
    #pragma unroll
    for (int t2 = 0; t2 < 4; ++t2)
      #pragma unroll
      for (int r = 0; r < 4; ++r)
        s[(rq + r) * 66 + t2 * 16 + l15] = cc[t2][r];
  }
  if (tid >= 928 && tid < 1024) {
    const int idx = tid - 928, r = idx / ACT_, k = idx - r * ACT_;
    al[r * 8 + k] = act[((size_t)(m0 + r) * T_ + t) * ACT_ + k];
  }
  __syncthreads();

  #pragma unroll
  for (int rep = 0; rep < 2; ++rep) {
    const int idx = rep * 1024 + tid;
    const int r = idx >> 7, c = idx & 127;
    const int base = (c < 64) ? 0 : 4, cl = c & 63, j = c & 31;
    float v = sh[base * 1056 + r * 66 + cl] + sh[(base + 1) * 1056 + r * 66 + cl]
            + sh[(base + 2) * 1056 + r * 66 + cl] + sh[(base + 3) * 1056 + r * 66 + cl];
    const size_t ob = ((size_t)(m0 + r) * T_ + t) * STO_ + j;
    const int sel = c >> 5;
    if (sel == 0) {
      if (nt == 0) pm[ob] = v + pr_mb[j];
    } else if (sel == 1) {
      if (nt == 0) ps[ob] = __expf(fminf(fmaxf(v + pr_sb[j], -5.f), 2.f));
    } else if (sel == 2) {
      const float x = v + po_mb[j];
      if (nt == 0) qm[ob] = x;
      zm[r * 32 + j] = x;
    } else {
      const float x = __expf(fminf(fmaxf(v + po_sb[j], -5.f), 2.f));
      if (nt == 0) qs[ob] = x;
      zs[r * 32 + j] = x;
    }
  }
  __syncthreads();

  if (tid < 512) {
    const int r = tid >> 5, j = tid & 31;
    const float z = zm[r * 32 + j] + zs[r * 32 + j] * eps[((size_t)(m0 + r) * T_ + t) * STO_ + j];
    zl[r * 32 + j] = z;
    if (nt == 0) feat[((size_t)(m0 + r) * T_ + t) * 1056 + 1024 + j] = z;
  }
  __syncthreads();

  {
    char* x1c = (char*)sh;
    const int n = tid;
    const float* w = in_w1 + (size_t)n * 38;
    float wreg[38];
    #pragma unroll
    for (int j = 0; j < 38; ++j) wreg[j] = w[j];
    const float bn = in_b1[n];
    const int chunk = n >> 3, sub = (n & 7) * 2;
    #pragma unroll 2
    for (int r = 0; r < 16; ++r) {
      float a = bn;
      #pragma unroll
      for (int k = 0; k < STO_; ++k) a = fmaf(zl[r * 32 + k], wreg[k], a);
      #pragma unroll
      for (int k = 0; k < ACT_; ++k) a = fmaf(al[r * 8 + k], wreg[32 + k], a);
      *(bf16*)(x1c + r * 2048 + ((chunk ^ (r & 7)) << 4) + sub) = (bf16)fmaxf(a, 0.f);
    }
  }
  __syncthreads();

  {
    const char* x1c = (const char*)sh;
    const int nfrag = wv & 7, kw2 = wv >> 3;
    const int col = nt * 128 + nfrag * 16 + l15;
    f32x4 e0{0.f,0.f,0.f,0.f};
    const bf16* __restrict__ wp = win2 + (size_t)col * 1024 + kw2 * 512 + kq;
    #pragma unroll 4
    for (int k = 0; k < 512; k += 32) {
      const int chunk = (kw2 * 512 + k + kq) >> 3;
      bf16x8 af = *(const bf16x8*)(x1c + l15 * 2048 + ((chunk ^ (l15 & 7)) << 4));
      e0 = MF(af, *(const bf16x8*)(wp + k), e0);
    }
    if (kw2) {
      float* s = shE + nfrag * 272;
      #pragma unroll
      for (int r = 0; r < 4; ++r) s[(rq + r) * 17 + l15] = e0[r];
    }
    __syncthreads();
    if (kw2 == 0) {
      const float* s = shE + nfrag * 272;
      const float bv = b_in2[col];
      #pragma unroll
      for (int r = 0; r < 4; ++r) {
        const float v = e0[r] + s[(rq + r) * 17 + l15] + bv;
        x2b[(size_t)(m0 + rq + r) * 1024 + col] = (bf16)fmaxf(v, 0.f);
      }
    }
  }
}

extern "C" void kernel_launch(void* const* d_in, const int* in_sizes, int n_in,
                              void* d_out, int out_size, void* d_ws, size_t ws_size,
                              hipStream_t stream) {
  (void)in_sizes; (void)n_in; (void)out_size; (void)ws_size;
  const float* obs      = (const float*)d_in[0];
  const float* actions  = (const float*)d_in[1];
  const float* eps_post = (const float*)d_in[3];   // eps_prior unused by the math
  const float* in_w1 = (const float*)d_in[4];
  const float* in_b1 = (const float*)d_in[5];
  const float* in_w2 = (const float*)d_in[6];
  const float* in_b2 = (const float*)d_in[7];
  const float* gru_wih = (const float*)d_in[8];
  const float* gru_whh = (const float*)d_in[9];
  const float* gru_bih = (const float*)d_in[10];
  const float* gru_bhh = (const float*)d_in[11];
  const float* pr_w1 = (const float*)d_in[12];
  const float* pr_b1 = (const float*)d_in[13];
  const float* pr_w2 = (const float*)d_in[14];
  const float* pr_b2 = (const float*)d_in[15];
  const float* pr_mw = (const float*)d_in[16];
  const float* pr_mb = (const float*)d_in[17];
  const float* pr_sw = (const float*)d_in[18];
  const float* pr_sb = (const float*)d_in[19];
  const float* po_w1 = (const float*)d_in[20];
  const float* po_b1 = (const float*)d_in[21];
  const float* po_w2 = (const float*)d_in[22];
  const float* po_b2 = (const float*)d_in[23];
  const float* po_mw = (const float*)d_in[24];
  const float* po_mb = (const float*)d_in[25];
  const float* po_sw = (const float*)d_in[26];
  const float* po_sb = (const float*)d_in[27];

  float* feat = (float*)d_out;
  float* pm = feat + (size_t)B_ * T_ * 1056;
  float* ps = pm + (size_t)B_ * T_ * STO_;
  float* qm = ps + (size_t)B_ * T_ * STO_;
  float* qs = qm + (size_t)B_ * T_ * STO_;

  char* wp_ = (char*)d_ws;
  auto carve = [&](size_t bytes) -> void* {
    void* r = (void*)wp_;
    wp_ += (bytes + 255) & ~(size_t)255;
    return r;
  };
  bf16* w_in2b  = (bf16*)carve((size_t)HID_ * HID_ * 2);
  bf16* w_wihb  = (bf16*)carve((size_t)3 * HID_ * HID_ * 2);
  bf16* w_whhb  = (bf16*)carve((size_t)3 * HID_ * HID_ * 2);
  bf16* w_pr1b  = (bf16*)carve((size_t)HID_ * HID_ * 2);
  bf16* w_pr2b  = (bf16*)carve((size_t)HID_ * HID_ * 2);
  bf16* w_po1hb = (bf16*)carve((size_t)HID_ * HID_ * 2);
  bf16* w_po1ob = (bf16*)carve((size_t)HID_ * OBS_ * 2);
  bf16* w_po2b  = (bf16*)carve((size_t)HID_ * HID_ * 2);
  bf16* w_headb = (bf16*)carve((size_t)128 * HID_ * 2);
  bf16* obsb    = (bf16*)carve((size_t)B_ * T_ * OBS_ * 2);
  bf16* x1b = (bf16*)carve((size_t)B_ * HID_ * 2);
  bf16* x2b = (bf16*)carve((size_t)B_ * HID_ * 2);
  bf16* hbA = (bf16*)carve((size_t)B_ * HID_ * 2);
  bf16* hbB = (bf16*)carve((size_t)B_ * HID_ * 2);
  bf16* p1b = (bf16*)carve((size_t)B_ * HID_ * 2);
  bf16* q1b = (bf16*)carve((size_t)B_ * HID_ * 2);
  bf16* p2b = (bf16*)carve((size_t)B_ * HID_ * 2);
  bf16* q2b = (bf16*)carve((size_t)B_ * HID_ * 2);
  float* hfA = (float*)carve((size_t)B_ * HID_ * 4);
  float* hfB = (float*)carve((size_t)B_ * HID_ * 4);

  CvtArgs ca = { in_w2, gru_wih, gru_whh, pr_w1, pr_w2, po_w1, po_w2,
                 pr_mw, pr_sw, po_mw, po_sw, obs,
                 w_in2b, w_wihb, w_whhb, w_pr1b, w_pr2b, w_po1hb, w_po1ob, w_po2b, w_headb, obsb };
  k_cvtall<<<dim3(28800), dim3(256), 0, stream>>>(ca);
  k_init<<<dim3(1024), dim3(256), 0, stream>>>(in_b1, x1b, hbA, hbB, hfA, hfB);

  // x2_0 = relu(x1_0 @ in_w2^T + b2)
  GB2 dummy = {};
  GB2 g_x2i = { x1b, nullptr, w_in2b, nullptr, in_b2, x2b, 1024, 0, 1024, 128 };
  k_l1<<<dim3(256), dim3(512), 0, stream>>>(g_x2i, dummy, 256);

  for (int t = 0; t < T_; ++t) {
    bf16* hbCur = (t & 1) ? hbB : hbA;
    bf16* hbPrev = (t & 1) ? hbA : hbB;
    float* hfCur = (t & 1) ? hfB : hfA;
    float* hfPrev = (t & 1) ? hfA : hfB;

    // K1: gh + gi + gates -> h, feat_h (512 blocks, 8 waves)
    k_gru<<<dim3(512), dim3(512), 0, stream>>>(
        hbPrev, hfPrev, hbCur, hfCur, x2b, w_wihb, w_whhb, gru_bih, gru_bhh, feat, t);

    // K2: pr1 (K=1024, kseg=128) || q1 (K=2048, kseg=256)
    GB2 g_pr1 = { hbCur, nullptr, w_pr1b, nullptr, pr_b1, p1b, 1024, 0, 1024, 128 };
    GB2 g_q1  = { hbCur, obsb + (size_t)t * 1024, w_po1hb, w_po1ob, po_b1, q1b,
                  1024, T_ * 1024, 1024, 256 };
    k_l1<<<dim3(512), dim3(512), 0, stream>>>(g_pr1, g_q1, 256);

    // K3: pr2 || po2 (kseg=128)
    GB2 g_pr2 = { p1b, nullptr, w_pr2b, nullptr, pr_b2, p2b, 1024, 0, 1024, 128 };
    GB2 g_po2 = { q1b, nullptr, w_po2b, nullptr, po_b2, q2b, 1024, 0, 1024, 128 };
    k_l1<<<dim3(512), dim3(512), 0, stream>>>(g_pr2, g_po2, 256);

    // K4: heads + stats + z + feat_z + x1(LDS) + next x2 (wide)
    k_fin3<<<dim3(128), dim3(1024), 0, stream>>>(
        p2b, q2b, w_headb, w_in2b, pr_mb, pr_sb, po_mb, po_sb, in_b2,
        eps_post, actions, in_w1, in_b1, pm, ps, qm, qs, feat, x2b, t);
  }
}

// Round 18
// 5576.935 us; speedup vs baseline: 1.6952x; 1.0008x over previous
//
#include <hip/hip_runtime.h>
#include <hip/hip_bf16.h>

#define B_   256
#define T_   64
#define OBS_ 1024
#define ACT_ 6
#define STO_ 32
#define HID_ 1024

using bf16 = __bf16;
typedef __attribute__((ext_vector_type(8))) __bf16 bf16x8;
typedef __attribute__((ext_vector_type(4))) float f32x4;

__device__ __forceinline__ f32x4 MF(bf16x8 a, bf16x8 b, f32x4 c) {
  return __builtin_amdgcn_mfma_f32_16x16x32_bf16(a, b, c, 0, 0, 0);
}

// ---------------- prologue: weights + obs -> bf16 ----------------
struct CvtArgs {
  const float *in_w2, *gru_wih, *gru_whh, *pr_w1, *pr_w2, *po_w1, *po_w2;
  const float *pr_mw, *pr_sw, *po_mw, *po_sw, *obs;
  bf16 *w_in2b, *w_wihb, *w_whhb, *w_pr1b, *w_pr2b, *w_po1hb, *w_po1ob, *w_po2b, *w_headb, *obsb;
};

__global__ void k_cvtall(CvtArgs a) {
  const int row = blockIdx.x;            // 28800 rows
  const float* src; bf16* dst;
  if      (row < 1024)  { src = a.in_w2   + (size_t)row * 1024;               dst = a.w_in2b  + (size_t)row * 1024; }
  else if (row < 4096)  { int r = row - 1024;  src = a.gru_wih + (size_t)r * 1024;        dst = a.w_wihb  + (size_t)r * 1024; }
  else if (row < 7168)  { int r = row - 4096;  src = a.gru_whh + (size_t)r * 1024;        dst = a.w_whhb  + (size_t)r * 1024; }
  else if (row < 8192)  { int r = row - 7168;  src = a.pr_w1   + (size_t)r * 1024;        dst = a.w_pr1b  + (size_t)r * 1024; }
  else if (row < 9216)  { int r = row - 8192;  src = a.pr_w2   + (size_t)r * 1024;        dst = a.w_pr2b  + (size_t)r * 1024; }
  else if (row < 10240) { int r = row - 9216;  src = a.po_w1   + (size_t)r * 2048;        dst = a.w_po1hb + (size_t)r * 1024; }
  else if (row < 11264) { int r = row - 10240; src = a.po_w1   + (size_t)r * 2048 + 1024; dst = a.w_po1ob + (size_t)r * 1024; }
  else if (row < 12288) { int r = row - 11264; src = a.po_w2   + (size_t)r * 1024;        dst = a.w_po2b  + (size_t)r * 1024; }
  else if (row < 12416) {
    int r = row - 12288;
    const float* hs[4] = { a.pr_mw, a.pr_sw, a.po_mw, a.po_sw };
    src = hs[r >> 5] + (size_t)(r & 31) * 1024;
    dst = a.w_headb + (size_t)r * 1024;
  }
  else { int r = row - 12416; src = a.obs + (size_t)r * 1024; dst = a.obsb + (size_t)r * 1024; }
  const int c = threadIdx.x * 4;
  float4 f = *(const float4*)(src + c);
  dst[c] = (bf16)f.x; dst[c + 1] = (bf16)f.y; dst[c + 2] = (bf16)f.z; dst[c + 3] = (bf16)f.w;
}

__global__ void k_init(const float* __restrict__ in_b1, bf16* __restrict__ x1b,
                       bf16* __restrict__ hbA, bf16* __restrict__ hbB,
                       float* __restrict__ hfA, float* __restrict__ hfB) {
  const int i = blockIdx.x * 256 + threadIdx.x;      // < 262144
  x1b[i] = (bf16)fmaxf(in_b1[i & 1023], 0.f);        // z0=0, a0=0
  hbA[i] = (bf16)0.f; hbB[i] = (bf16)0.f;
  hfA[i] = 0.f; hfB[i] = 0.f;
}

// ---- load-all-then-MFMA core: NCH chunks of 128 K (20 loads in flight/chunk) ----
template<int NCH>
__device__ __forceinline__ void gb2_core(const bf16* __restrict__ ap,
                                         const bf16* __restrict__ wp, f32x4* cc) {
  #pragma unroll
  for (int ch = 0; ch < NCH; ++ch) {
    bf16x8 afv[4], wfv[4][4];
    #pragma unroll
    for (int i = 0; i < 4; ++i) {
      const int k = ch * 128 + i * 32;
      afv[i] = *(const bf16x8*)(ap + k);
      #pragma unroll
      for (int j = 0; j < 4; ++j)
        wfv[i][j] = *(const bf16x8*)(wp + j * 16384 + k);
    }
    #pragma unroll
    for (int i = 0; i < 4; ++i)
      #pragma unroll
      for (int j = 0; j < 4; ++j)
        cc[j] = MF(afv[i], wfv[i][j], cc[j]);
  }
}

// ---------------- split-K dual-GEMM, 8 waves, two K-segments, bf16 out ----------------
struct GB2 {
  const bf16 *A1, *A2, *W1, *W2;
  const float* bias;
  bf16* out;
  int lda1, lda2, K1, kseg;
};

template<int NCH>
__device__ __forceinline__ void gb2_run(const GB2& g, int tile, float* sh) {
  const int tid = threadIdx.x, lane = tid & 63, kw = tid >> 6;   // kw 0..7
  const int l15 = lane & 15, kg = lane >> 4, kq = kg * 8, rq = kg * 4;
  const int m0 = (tile >> 4) * 16, n0 = (tile & 15) * 64;
  const int kb = kw * g.kseg;

  const bf16* __restrict__ ap;
  const bf16* __restrict__ wp;
  if (kb < g.K1) {
    ap = g.A1 + (size_t)(m0 + l15) * g.lda1 + kb + kq;
    wp = g.W1 + (size_t)(n0 + l15) * 1024 + kb + kq;
  } else {
    ap = g.A2 + (size_t)(m0 + l15) * g.lda2 + (kb - g.K1) + kq;
    wp = g.W2 + (size_t)(n0 + l15) * 1024 + (kb - g.K1) + kq;
  }
  f32x4 cc[4];
  #pragma unroll
  for (int j = 0; j < 4; ++j) cc[j] = f32x4{0.f, 0.f, 0.f, 0.f};
  gb2_core<NCH>(ap, wp, cc);

  if (kw) {
    float* s = sh + (kw - 1) * 1056;
    #pragma unroll
    for (int t2 = 0; t2 < 4; ++t2)
      #pragma unroll
      for (int r = 0; r < 4; ++r)
        s[(rq + r) * 66 + t2 * 16 + l15] = cc[t2][r];
  }
  __syncthreads();
  if (kw == 0) {
    #pragma unroll
    for (int t2 = 0; t2 < 4; ++t2) {
      const int n = n0 + t2 * 16 + l15;
      const float bv = g.bias[n];
      #pragma unroll
      for (int r = 0; r < 4; ++r) {
        float v = cc[t2][r] + bv;
        #pragma unroll
        for (int s = 0; s < 7; ++s)
          v += sh[s * 1056 + (rq + r) * 66 + t2 * 16 + l15];
        g.out[(size_t)(m0 + rq + r) * 1024 + n] = (bf16)fmaxf(v, 0.f);
      }
    }
  }
}

template<int NCH0, int NCH1>
__global__ __launch_bounds__(512, 2) void k_l1(GB2 g0, GB2 g1, int s1) {
  __shared__ float sh[7 * 1056];
  if ((int)blockIdx.x < s1) gb2_run<NCH0>(g0, blockIdx.x, sh);
  else                      gb2_run<NCH1>(g1, blockIdx.x - s1, sh);
}

// ---------------- gh + gi + GRU gates fused (R12-verified numerics, 8mt x 64cs) ----------------
// 512 blocks: mt = bid>>6 (0..7, 32 rows), cs = bid&63 (16 gate-cols; XCD = cs%8).
// 8 waves = 2 msub x 4 kw; kseg 256 (2 chunks of 128 per matrix, 16 loads in flight).
__global__ __launch_bounds__(512, 2) void k_gru(
    const bf16* __restrict__ hbPrev, const float* __restrict__ hfPrev,
    bf16* __restrict__ hbCur, float* __restrict__ hfCur,
    const bf16* __restrict__ x2b, const bf16* __restrict__ wih,
    const bf16* __restrict__ whh, const float* __restrict__ bih,
    const float* __restrict__ bhh, float* __restrict__ feat, int t) {
  __shared__ float sh[6 * 1088];
  const int mt = blockIdx.x >> 6, cs = blockIdx.x & 63;
  const int tid = threadIdx.x, lane = tid & 63, wv = tid >> 6;
  const int msub = wv & 1, kw = wv >> 1;          // msub 0..1, kw 0..3
  const int l15 = lane & 15, kg = lane >> 4, kq = kg * 8, rq = kg * 4;
  const int mrow = mt * 32 + msub * 16;
  const int c0 = cs * 16;
  const int kb = kw * 256;
  const size_t GOFF = (size_t)1024 * 1024;

  f32x4 ghR{0.f,0.f,0.f,0.f}, ghZ = ghR, ghN = ghR, giR = ghR, giZ = ghR, giN = ghR;
  {
    const bf16* __restrict__ ap = hbPrev + (size_t)(mrow + l15) * 1024 + kb + kq;
    const bf16* __restrict__ wr = whh + (size_t)(c0 + l15) * 1024 + kb + kq;
    #pragma unroll
    for (int ch = 0; ch < 2; ++ch) {
      bf16x8 afv[4], wrv[4], wzv[4], wnv[4];
      #pragma unroll
      for (int i = 0; i < 4; ++i) {
        const int k = ch * 128 + i * 32;
        afv[i] = *(const bf16x8*)(ap + k);
        wrv[i] = *(const bf16x8*)(wr + k);
        wzv[i] = *(const bf16x8*)(wr + GOFF + k);
        wnv[i] = *(const bf16x8*)(wr + 2 * GOFF + k);
      }
      #pragma unroll
      for (int i = 0; i < 4; ++i) {
        ghR = MF(afv[i], wrv[i], ghR);
        ghZ = MF(afv[i], wzv[i], ghZ);
        ghN = MF(afv[i], wnv[i], ghN);
      }
    }
  }
  {
    const bf16* __restrict__ ap = x2b + (size_t)(mrow + l15) * 1024 + kb + kq;
    const bf16* __restrict__ wr = wih + (size_t)(c0 + l15) * 1024 + kb + kq;
    #pragma unroll
    for (int ch = 0; ch < 2; ++ch) {
      bf16x8 afv[4], wrv[4], wzv[4], wnv[4];
      #pragma unroll
      for (int i = 0; i < 4; ++i) {
        const int k = ch * 128 + i * 32;
        afv[i] = *(const bf16x8*)(ap + k);
        wrv[i] = *(const bf16x8*)(wr + k);
        wzv[i] = *(const bf16x8*)(wr + GOFF + k);
        wnv[i] = *(const bf16x8*)(wr + 2 * GOFF + k);
      }
      #pragma unroll
      for (int i = 0; i < 4; ++i) {
        giR = MF(afv[i], wrv[i], giR);
        giZ = MF(afv[i], wzv[i], giZ);
        giN = MF(afv[i], wnv[i], giN);
      }
    }
  }
  f32x4 sR = ghR + giR, sZ = ghZ + giZ;
  if (kw) {
    float* s = sh + (msub * 3 + (kw - 1)) * 1088;
    #pragma unroll
    for (int r = 0; r < 4; ++r) {
      s[      (rq + r) * 17 + l15] = sR[r];
      s[272 + (rq + r) * 17 + l15] = sZ[r];
      s[544 + (rq + r) * 17 + l15] = giN[r];
      s[816 + (rq + r) * 17 + l15] = ghN[r];
    }
  }
  __syncthreads();
  if (kw == 0) {
    const int c = c0 + l15;
    const float bir = bih[c], biz = bih[1024 + c], bin_ = bih[2048 + c];
    const float bhr = bhh[c], bhz = bhh[1024 + c], bhn = bhh[2048 + c];
    #pragma unroll
    for (int r = 0; r < 4; ++r) {
      float vr = sR[r], vz = sZ[r], vin = giN[r], vhn = ghN[r];
      #pragma unroll
      for (int sidx = 0; sidx < 3; ++sidx) {
        const float* s = sh + (msub * 3 + sidx) * 1088;
        vr  += s[      (rq + r) * 17 + l15];
        vz  += s[272 + (rq + r) * 17 + l15];
        vin += s[544 + (rq + r) * 17 + l15];
        vhn += s[816 + (rq + r) * 17 + l15];
      }
      const int row = mrow + rq + r;
      float rr = vr + bir + bhr;
      float zz = vz + biz + bhz;
      rr = 1.f / (1.f + __expf(-rr));
      zz = 1.f / (1.f + __expf(-zz));
      const float nn = tanhf(vin + bin_ + rr * (vhn + bhn));
      const float h2 = (1.f - zz) * nn + zz * hfPrev[(size_t)row * 1024 + c];
      hbCur[(size_t)row * 1024 + c] = (bf16)h2;
      hfCur[(size_t)row * 1024 + c] = h2;
      feat[((size_t)row * T_ + t) * 1056 + c] = h2;
    }
  }
}

// ---------------- heads + stats + z + feat_z + x1(LDS) + next x2 (WIDE, R14-verified) ----------------
__global__ __launch_bounds__(1024, 1) void k_fin3(
    const bf16* __restrict__ p2b, const bf16* __restrict__ q2b,
    const bf16* __restrict__ whead, const bf16* __restrict__ win2,
    const float* __restrict__ pr_mb, const float* __restrict__ pr_sb,
    const float* __restrict__ po_mb, const float* __restrict__ po_sb,
    const float* __restrict__ b_in2,
    const float* __restrict__ eps, const float* __restrict__ act,
    const float* __restrict__ in_w1, const float* __restrict__ in_b1,
    float* __restrict__ pm, float* __restrict__ ps,
    float* __restrict__ qm, float* __restrict__ qs,
    float* __restrict__ feat, bf16* __restrict__ x2b, int t) {
  __shared__ float sh[12288];
  const int g = blockIdx.x >> 3, nt = blockIdx.x & 7, m0 = g * 16;
  const int tid = threadIdx.x, lane = tid & 63, wv = tid >> 6;
  const int l15 = lane & 15, kg = lane >> 4, kq = kg * 8, rq = kg * 4;
  float* zm = sh + 8448;
  float* zs = sh + 8960;
  float* zl = sh + 9472;
  float* al = sh + 9984;
  float* shE = sh + 10112;

  if (wv < 8) {
    const int kw = wv & 3, half = wv >> 2;
    const bf16* __restrict__ A = half ? q2b : p2b;
    const bf16* __restrict__ ap = A + (size_t)(m0 + l15) * 1024 + kw * 256 + kq;
    const bf16* __restrict__ wp = whead + (size_t)(half * 64 + l15) * 1024 + kw * 256 + kq;
    f32x4 cc[4];
    #pragma unroll
    for (int j = 0; j < 4; ++j) cc[j] = f32x4{0.f, 0.f, 0.f, 0.f};
    gb2_core<2>(ap, wp, cc);
    float* s = sh + wv * 1056;
    #pragma unroll
    for (int t2 = 0; t2 < 4; ++t2)
      #pragma unroll
      for (int r = 0; r < 4; ++r)
        s[(rq + r) * 66 + t2 * 16 + l15] = cc[t2][r];
  }
  if (tid >= 928 && tid < 1024) {
    const int idx = tid - 928, r = idx / ACT_, k = idx - r * ACT_;
    al[r * 8 + k] = act[((size_t)(m0 + r) * T_ + t) * ACT_ + k];
  }
  __syncthreads();

  #pragma unroll
  for (int rep = 0; rep < 2; ++rep) {
    const int idx = rep * 1024 + tid;
    const int r = idx >> 7, c = idx & 127;
    const int base = (c < 64) ? 0 : 4, cl = c & 63, j = c & 31;
    float v = sh[base * 1056 + r * 66 + cl] + sh[(base + 1) * 1056 + r * 66 + cl]
            + sh[(base + 2) * 1056 + r * 66 + cl] + sh[(base + 3) * 1056 + r * 66 + cl];
    const size_t ob = ((size_t)(m0 + r) * T_ + t) * STO_ + j;
    const int sel = c >> 5;
    if (sel == 0) {
      if (nt == 0) pm[ob] = v + pr_mb[j];
    } else if (sel == 1) {
      if (nt == 0) ps[ob] = __expf(fminf(fmaxf(v + pr_sb[j], -5.f), 2.f));
    } else if (sel == 2) {
      const float x = v + po_mb[j];
      if (nt == 0) qm[ob] = x;
      zm[r * 32 + j] = x;
    } else {
      const float x = __expf(fminf(fmaxf(v + po_sb[j], -5.f), 2.f));
      if (nt == 0) qs[ob] = x;
      zs[r * 32 + j] = x;
    }
  }
  __syncthreads();

  if (tid < 512) {
    const int r = tid >> 5, j = tid & 31;
    const float z = zm[r * 32 + j] + zs[r * 32 + j] * eps[((size_t)(m0 + r) * T_ + t) * STO_ + j];
    zl[r * 32 + j] = z;
    if (nt == 0) feat[((size_t)(m0 + r) * T_ + t) * 1056 + 1024 + j] = z;
  }
  __syncthreads();

  {
    char* x1c = (char*)sh;
    const int n = tid;
    const float* w = in_w1 + (size_t)n * 38;
    float wreg[38];
    #pragma unroll
    for (int j = 0; j < 38; ++j) wreg[j] = w[j];
    const float bn = in_b1[n];
    const int chunk = n >> 3, sub = (n & 7) * 2;
    #pragma unroll 2
    for (int r = 0; r < 16; ++r) {
      float a = bn;
      #pragma unroll
      for (int k = 0; k < STO_; ++k) a = fmaf(zl[r * 32 + k], wreg[k], a);
      #pragma unroll
      for (int k = 0; k < ACT_; ++k) a = fmaf(al[r * 8 + k], wreg[32 + k], a);
      *(bf16*)(x1c + r * 2048 + ((chunk ^ (r & 7)) << 4) + sub) = (bf16)fmaxf(a, 0.f);
    }
  }
  __syncthreads();

  {
    const char* x1c = (const char*)sh;
    const int nfrag = wv & 7, kw2 = wv >> 3;
    const int col = nt * 128 + nfrag * 16 + l15;
    f32x4 e0{0.f,0.f,0.f,0.f};
    const bf16* __restrict__ wp = win2 + (size_t)col * 1024 + kw2 * 512 + kq;
    #pragma unroll
    for (int ch = 0; ch < 2; ++ch) {
      bf16x8 wfv[8];
      #pragma unroll
      for (int i = 0; i < 8; ++i)
        wfv[i] = *(const bf16x8*)(wp + ch * 256 + i * 32);
      #pragma unroll
      for (int i = 0; i < 8; ++i) {
        const int k = kw2 * 512 + ch * 256 + i * 32 + kq;
        const int chunk = k >> 3;
        bf16x8 af = *(const bf16x8*)(x1c + l15 * 2048 + ((chunk ^ (l15 & 7)) << 4));
        e0 = MF(af, wfv[i], e0);
      }
    }
    if (kw2) {
      float* s = shE + nfrag * 272;
      #pragma unroll
      for (int r = 0; r < 4; ++r) s[(rq + r) * 17 + l15] = e0[r];
    }
    __syncthreads();
    if (kw2 == 0) {
      const float* s = shE + nfrag * 272;
      const float bv = b_in2[col];
      #pragma unroll
      for (int r = 0; r < 4; ++r) {
        const float v = e0[r] + s[(rq + r) * 17 + l15] + bv;
        x2b[(size_t)(m0 + rq + r) * 1024 + col] = (bf16)fmaxf(v, 0.f);
      }
    }
  }
}

extern "C" void kernel_launch(void* const* d_in, const int* in_sizes, int n_in,
                              void* d_out, int out_size, void* d_ws, size_t ws_size,
                              hipStream_t stream) {
  (void)in_sizes; (void)n_in; (void)out_size; (void)ws_size;
  const float* obs      = (const float*)d_in[0];
  const float* actions  = (const float*)d_in[1];
  const float* eps_post = (const float*)d_in[3];   // eps_prior unused by the math
  const float* in_w1 = (const float*)d_in[4];
  const float* in_b1 = (const float*)d_in[5];
  const float* in_w2 = (const float*)d_in[6];
  const float* in_b2 = (const float*)d_in[7];
  const float* gru_wih = (const float*)d_in[8];
  const float* gru_whh = (const float*)d_in[9];
  const float* gru_bih = (const float*)d_in[10];
  const float* gru_bhh = (const float*)d_in[11];
  const float* pr_w1 = (const float*)d_in[12];
  const float* pr_b1 = (const float*)d_in[13];
  const float* pr_w2 = (const float*)d_in[14];
  const float* pr_b2 = (const float*)d_in[15];
  const float* pr_mw = (const float*)d_in[16];
  const float* pr_mb = (const float*)d_in[17];
  const float* pr_sw = (const float*)d_in[18];
  const float* pr_sb = (const float*)d_in[19];
  const float* po_w1 = (const float*)d_in[20];
  const float* po_b1 = (const float*)d_in[21];
  const float* po_w2 = (const float*)d_in[22];
  const float* po_b2 = (const float*)d_in[23];
  const float* po_mw = (const float*)d_in[24];
  const float* po_mb = (const float*)d_in[25];
  const float* po_sw = (const float*)d_in[26];
  const float* po_sb = (const float*)d_in[27];

  float* feat = (float*)d_out;
  float* pm = feat + (size_t)B_ * T_ * 1056;
  float* ps = pm + (size_t)B_ * T_ * STO_;
  float* qm = ps + (size_t)B_ * T_ * STO_;
  float* qs = qm + (size_t)B_ * T_ * STO_;

  char* wp_ = (char*)d_ws;
  auto carve = [&](size_t bytes) -> void* {
    void* r = (void*)wp_;
    wp_ += (bytes + 255) & ~(size_t)255;
    return r;
  };
  bf16* w_in2b  = (bf16*)carve((size_t)HID_ * HID_ * 2);
  bf16* w_wihb  = (bf16*)carve((size_t)3 * HID_ * HID_ * 2);
  bf16* w_whhb  = (bf16*)carve((size_t)3 * HID_ * HID_ * 2);
  bf16* w_pr1b  = (bf16*)carve((size_t)HID_ * HID_ * 2);
  bf16* w_pr2b  = (bf16*)carve((size_t)HID_ * HID_ * 2);
  bf16* w_po1hb = (bf16*)carve((size_t)HID_ * HID_ * 2);
  bf16* w_po1ob = (bf16*)carve((size_t)HID_ * OBS_ * 2);
  bf16* w_po2b  = (bf16*)carve((size_t)HID_ * HID_ * 2);
  bf16* w_headb = (bf16*)carve((size_t)128 * HID_ * 2);
  bf16* obsb    = (bf16*)carve((size_t)B_ * T_ * OBS_ * 2);
  bf16* x1b = (bf16*)carve((size_t)B_ * HID_ * 2);
  bf16* x2b = (bf16*)carve((size_t)B_ * HID_ * 2);
  bf16* hbA = (bf16*)carve((size_t)B_ * HID_ * 2);
  bf16* hbB = (bf16*)carve((size_t)B_ * HID_ * 2);
  bf16* p1b = (bf16*)carve((size_t)B_ * HID_ * 2);
  bf16* q1b = (bf16*)carve((size_t)B_ * HID_ * 2);
  bf16* p2b = (bf16*)carve((size_t)B_ * HID_ * 2);
  bf16* q2b = (bf16*)carve((size_t)B_ * HID_ * 2);
  float* hfA = (float*)carve((size_t)B_ * HID_ * 4);
  float* hfB = (float*)carve((size_t)B_ * HID_ * 4);

  CvtArgs ca = { in_w2, gru_wih, gru_whh, pr_w1, pr_w2, po_w1, po_w2,
                 pr_mw, pr_sw, po_mw, po_sw, obs,
                 w_in2b, w_wihb, w_whhb, w_pr1b, w_pr2b, w_po1hb, w_po1ob, w_po2b, w_headb, obsb };
  k_cvtall<<<dim3(28800), dim3(256), 0, stream>>>(ca);
  k_init<<<dim3(1024), dim3(256), 0, stream>>>(in_b1, x1b, hbA, hbB, hfA, hfB);

  // x2_0 = relu(x1_0 @ in_w2^T + b2)
  GB2 dummy = {};
  GB2 g_x2i = { x1b, nullptr, w_in2b, nullptr, in_b2, x2b, 1024, 0, 1024, 128 };
  k_l1<1, 1><<<dim3(256), dim3(512), 0, stream>>>(g_x2i, dummy, 256);

  for (int t = 0; t < T_; ++t) {
    bf16* hbCur = (t & 1) ? hbB : hbA;
    bf16* hbPrev = (t & 1) ? hbA : hbB;
    float* hfCur = (t & 1) ? hfB : hfA;
    float* hfPrev = (t & 1) ? hfA : hfB;

    // K1: gh + gi + gates -> h, feat_h (512 blocks, 8 waves)
    k_gru<<<dim3(512), dim3(512), 0, stream>>>(
        hbPrev, hfPrev, hbCur, hfCur, x2b, w_wihb, w_whhb, gru_bih, gru_bhh, feat, t);

    // K2: pr1 (K=1024, kseg=128) || q1 (K=2048, kseg=256)
    GB2 g_pr1 = { hbCur, nullptr, w_pr1b, nullptr, pr_b1, p1b, 1024, 0, 1024, 128 };
    GB2 g_q1  = { hbCur, obsb + (size_t)t * 1024, w_po1hb, w_po1ob, po_b1, q1b,
                  1024, T_ * 1024, 1024, 256 };
    k_l1<1, 2><<<dim3(512), dim3(512), 0, stream>>>(g_pr1, g_q1, 256);

    // K3: pr2 || po2 (kseg=128)
    GB2 g_pr2 = { p1b, nullptr, w_pr2b, nullptr, pr_b2, p2b, 1024, 0, 1024, 128 };
    GB2 g_po2 = { q1b, nullptr, w_po2b, nullptr, po_b2, q2b, 1024, 0, 1024, 128 };
    k_l1<1, 1><<<dim3(512), dim3(512), 0, stream>>>(g_pr2, g_po2, 256);

    // K4: heads + stats + z + feat_z + x1(LDS) + next x2 (wide)
    k_fin3<<<dim3(128), dim3(1024), 0, stream>>>(
        p2b, q2b, w_headb, w_in2b, pr_mb, pr_sb, po_mb, po_sb, in_b2,
        eps_post, actions, in_w1, in_b1, pm, ps, qm, qs, feat, x2b, t);
  }
}